// Round 1
// baseline (456.111 us; speedup 1.0000x reference)
//
#include <hip/hip_runtime.h>
#include <hip/hip_bf16.h>
#include <cstddef>

#define NNODES 100000
#define NEDGES 1600000
#define CIN 128
#define HID 256
#define ACT 20
#define NGRAPH (NNODES / ACT)
#define BSHIFT 8
#define NB ((NNODES + 255) >> 8)     // 391 buckets of 256 nodes
#define BIN_WGS 512
#define PER_WG (NEDGES / BIN_WGS)    // 3125
#define CAP 8192                     // bucket window capacity (mean fill 4096)
#define NSLICE 8
#define PLANE ((size_t)NNODES * 16)  // elements per channel-plane of xws

typedef __attribute__((ext_vector_type(8))) short short8;
typedef __attribute__((ext_vector_type(4))) float f32x4;

__device__ __forceinline__ unsigned short f2b(float f) {
    unsigned u = __float_as_uint(f);
    u += 0x7FFF + ((u >> 16) & 1);          // round-to-nearest-even
    return (unsigned short)(u >> 16);
}
__device__ __forceinline__ float b2f(unsigned short h) {
    return __uint_as_float(((unsigned)h) << 16);
}

// ---------------- bucketed CSR build (fixed-capacity windows) ----------------

__global__ __launch_bounds__(256) void bin_k(const int* __restrict__ ei,
                                             int* __restrict__ bfill,
                                             unsigned* __restrict__ entries) {
    __shared__ int cnt[NB], lofs[NB], base[NB], cur[NB];
    __shared__ unsigned lbuf[PER_WG];
    __shared__ int gdst[PER_WG];
    __shared__ int wsum[4];
    const int t = threadIdx.x;
    for (int i = t; i < NB; i += 256) { cnt[i] = 0; cur[i] = 0; }
    __syncthreads();
    const int s = blockIdx.x * PER_WG;
    const int e = s + PER_WG;
    for (int i = s + t; i < e; i += 256)
        atomicAdd(&cnt[ei[NEDGES + i] >> BSHIFT], 1);
    __syncthreads();
    int c0 = (2 * t < NB) ? cnt[2 * t] : 0;
    int c1 = (2 * t + 1 < NB) ? cnt[2 * t + 1] : 0;
    int v = c0 + c1;
    int lane = t & 63, wid = t >> 6;
    int inc = v;
#pragma unroll
    for (int o = 1; o < 64; o <<= 1) {
        int tv = __shfl_up(inc, o, 64);
        if (lane >= o) inc += tv;
    }
    if (lane == 63) wsum[wid] = inc;
    __syncthreads();
    int woff = 0;
#pragma unroll
    for (int w = 0; w < 4; ++w) woff += (w < wid) ? wsum[w] : 0;
    int excl = inc + woff - v;
    if (2 * t < NB) lofs[2 * t] = excl;
    if (2 * t + 1 < NB) lofs[2 * t + 1] = excl + c0;
    __syncthreads();
    for (int b = t; b < NB; b += 256)
        base[b] = cnt[b] ? atomicAdd(&bfill[b], cnt[b]) : 0;
    __syncthreads();
    for (int i = s + t; i < e; i += 256) {
        int src = ei[i], dst = ei[NEDGES + i];
        int b = dst >> BSHIFT;
        int r = atomicAdd(&cur[b], 1);
        int slot = lofs[b] + r;
        lbuf[slot] = ((unsigned)src << 8) | (unsigned)(dst & 255);
        int g = base[b] + r;
        gdst[slot] = (g < CAP) ? (int)((size_t)b * CAP + g) : -1;
    }
    __syncthreads();
    for (int i = t; i < PER_WG; i += 256) {
        int g = gdst[i];
        if (g >= 0) entries[g] = lbuf[i];
    }
}

__global__ __launch_bounds__(256) void bucket_build_k(
    const unsigned* __restrict__ entries, const int* __restrict__ bfill,
    int2* __restrict__ rowptr2, int* __restrict__ csr, float* __restrict__ dinv) {
    const int b = blockIdx.x;
    const int count = min(bfill[b], CAP);
    const int node0 = b << BSHIFT;
    const int nn = min(256, NNODES - node0);
    const size_t gbase = (size_t)b * CAP;
    __shared__ int cnt[256], off[256], cur[256];
    const int t = threadIdx.x;
    cnt[t] = 0; cur[t] = 0;
    __syncthreads();
    for (int i = t; i < count; i += 256)
        atomicAdd(&cnt[entries[gbase + i] & 255], 1);
    __syncthreads();
    int lane = t & 63, wid = t >> 6;
    int v = cnt[t];
    int inc = v;
#pragma unroll
    for (int o = 1; o < 64; o <<= 1) {
        int tv = __shfl_up(inc, o, 64);
        if (lane >= o) inc += tv;
    }
    __shared__ int wsum[4];
    if (lane == 63) wsum[wid] = inc;
    __syncthreads();
    int woff = 0;
#pragma unroll
    for (int w = 0; w < 4; ++w) woff += (w < wid) ? wsum[w] : 0;
    int excl = inc + woff - v;
    off[t] = excl;
    if (t < nn) {
        rowptr2[node0 + t] = make_int2((int)gbase + excl, (int)gbase + excl + v);
        dinv[node0 + t] = rsqrtf(1.0f + (float)v);
    }
    __syncthreads();
    for (int i = t; i < count; i += 256) {
        unsigned en = entries[gbase + i];
        int loc = (int)(en & 255);
        int r = atomicAdd(&cur[loc], 1);
        csr[gbase + off[loc] + r] = (int)(en >> 8);
    }
}

// ---------------- weight conversions (single launch) ----------------

__global__ void cvt_w_k(const float* __restrict__ conv_w,
                        const float* __restrict__ lin1_w,
                        const float* __restrict__ lin2_w,
                        unsigned short* __restrict__ wt0,
                        unsigned short* __restrict__ wt1,
                        unsigned short* __restrict__ wt2) {
    int id = blockIdx.x * 256 + threadIdx.x;
    if (id < 16384) {
        int k = id >> 7, n = id & 127;
        wt0[n * 128 + k] = f2b(conv_w[k * 128 + n]);
    } else if (id < 16384 + 32768) {
        int i = id - 16384;
        wt1[i] = f2b(lin1_w[i]);
    } else if (id < 16384 + 32768 + 65536) {
        int i = id - 49152;
        wt2[i] = f2b(lin2_w[i]);
    }
}

// ---------------- MFMA bf16 GEMM for conv (fp32 A, reg-pipelined) ----------
// C-write now goes to the PLANE-SLICED xws layout:
//   plane p = channels [16p, 16p+16), stored node-major: xws[p*PLANE + row*16 + c]
// so each XCD's gather slice is a contiguous 3.2 MB region (L2-resident).

__global__ __launch_bounds__(256) void mgemm0_k(
    const float* __restrict__ Af, const unsigned short* __restrict__ B,
    const float* __restrict__ dinv, unsigned short* __restrict__ Cout, int M)
{
    const int tid = threadIdx.x;
    const int wid = tid >> 6;
    const int lane = tid & 63;
    const int quad = lane >> 4;
    const int l16 = lane & 15;
    const int bm = blockIdx.x * 128 + (wid >> 1) * 64;
    const int bn = (wid & 1) * 64;

    const float* pa[4];
    const unsigned short* pb[4];
#pragma unroll
    for (int t = 0; t < 4; ++t) {
        int m = bm + t * 16 + l16; if (m >= M) m = M - 1;   // clamp; store guarded
        pa[t] = Af + (size_t)m * 128 + quad * 8;
        int n = bn + t * 16 + l16;
        pb[t] = B + (size_t)n * 128 + quad * 8;
    }

    f32x4 acc[4][4];
#pragma unroll
    for (int i = 0; i < 4; ++i)
#pragma unroll
        for (int j = 0; j < 4; ++j) {
            f32x4 z = {0.f, 0.f, 0.f, 0.f};
            acc[i][j] = z;
        }

    float4 afl[2][4][2];
    short8 bf[2][4];
#pragma unroll
    for (int t = 0; t < 4; ++t) {
        afl[0][t][0] = *reinterpret_cast<const float4*>(pa[t]);
        afl[0][t][1] = *reinterpret_cast<const float4*>(pa[t] + 4);
        bf[0][t] = *reinterpret_cast<const short8*>(pb[t]);
    }

#pragma unroll
    for (int kt = 0; kt < 4; ++kt) {
        const int cur = kt & 1, nxt = cur ^ 1;
        if (kt < 3) {
#pragma unroll
            for (int t = 0; t < 4; ++t) {
                afl[nxt][t][0] = *reinterpret_cast<const float4*>(pa[t] + (kt + 1) * 32);
                afl[nxt][t][1] = *reinterpret_cast<const float4*>(pa[t] + (kt + 1) * 32 + 4);
                bf[nxt][t] = *reinterpret_cast<const short8*>(pb[t] + (kt + 1) * 32);
            }
        }
        short8 a[4];
#pragma unroll
        for (int t = 0; t < 4; ++t) {
            float4 f0 = afl[cur][t][0], f1 = afl[cur][t][1];
            short8 av;
            av[0] = (short)f2b(f0.x); av[1] = (short)f2b(f0.y);
            av[2] = (short)f2b(f0.z); av[3] = (short)f2b(f0.w);
            av[4] = (short)f2b(f1.x); av[5] = (short)f2b(f1.y);
            av[6] = (short)f2b(f1.z); av[7] = (short)f2b(f1.w);
            a[t] = av;
        }
#pragma unroll
        for (int i = 0; i < 4; ++i)
#pragma unroll
            for (int j = 0; j < 4; ++j)
                acc[i][j] = __builtin_amdgcn_mfma_f32_16x16x32_bf16(a[i], bf[cur][j], acc[i][j], 0, 0, 0);
    }

#pragma unroll
    for (int i = 0; i < 4; ++i)
#pragma unroll
        for (int r = 0; r < 4; ++r) {
            int row = bm + i * 16 + quad * 4 + r;
            if (row >= M) continue;
            float dv = dinv[row];
#pragma unroll
            for (int j = 0; j < 4; ++j) {
                // col = bn + j*16 + l16; plane = col>>4 = (bn>>4)+j; within = l16
                size_t pbase = (size_t)((bn >> 4) + j) * PLANE;
                Cout[pbase + (size_t)row * 16 + l16] = f2b(acc[i][j][r] * dv);
            }
        }
}

// ---------------- gather v6: XCD-sliced channel gather ----------------
// slice = blockIdx & 7 -> round-robin block->XCD dispatch pins each 3.2 MB
// xws plane to one XCD's L2. Per edge, 4 lanes read 8 B each (32 B slice row).
// 16 edge-slots per wave; butterfly-reduce over edge-slots; lanes 0..3 write
// the node's 16-channel h0 slice. Residual +x moved to fmlp_k.

__global__ __launch_bounds__(256) void gather_k(
    const int2* __restrict__ rowptr2, const int* __restrict__ csr,
    const unsigned short* __restrict__ xws, const float* __restrict__ dinv,
    const float* __restrict__ conv_b, unsigned short* __restrict__ h0)
{
    const int slice = blockIdx.x & 7;
    const int ng = blockIdx.x >> 3;
    const int wave = threadIdx.x >> 6;
    const int lane = threadIdx.x & 63;
    const int eslot = lane >> 2;      // 0..15: edge slot
    const int cq = lane & 3;          // channel quad within the 16-ch slice
    const unsigned short* xp = xws + (size_t)slice * PLANE;

#pragma unroll 1
    for (int ni = 0; ni < 8; ++ni) {
        const int node = ng * 32 + wave * 8 + ni;
        const int2 se = rowptr2[node];
        const int start = se.x, end = se.y;

        float a0 = 0.f, a1 = 0.f, a2 = 0.f, a3 = 0.f;
        if (eslot == 0) {              // self-loop contribution
            uint2 v = *reinterpret_cast<const uint2*>(xp + (size_t)node * 16 + cq * 4);
            a0 = __uint_as_float(v.x << 16);
            a1 = __uint_as_float(v.x & 0xffff0000u);
            a2 = __uint_as_float(v.y << 16);
            a3 = __uint_as_float(v.y & 0xffff0000u);
        }

        for (int p = start; p < end; p += 32) {
            uint2 r[2];
            int valid[2];
#pragma unroll
            for (int j = 0; j < 2; ++j) {
                int e = p + j * 16 + eslot;
                bool ok = e < end;
                int idx = ok ? csr[e] : node;
                r[j] = *reinterpret_cast<const uint2*>(xp + (size_t)idx * 16 + cq * 4);
                valid[j] = ok;
            }
#pragma unroll
            for (int j = 0; j < 2; ++j)
                if (valid[j]) {
                    a0 += __uint_as_float(r[j].x << 16);
                    a1 += __uint_as_float(r[j].x & 0xffff0000u);
                    a2 += __uint_as_float(r[j].y << 16);
                    a3 += __uint_as_float(r[j].y & 0xffff0000u);
                }
        }

        // reduce across the 16 edge slots (same cq -> xor over eslot bits)
#pragma unroll
        for (int m = 4; m < 64; m <<= 1) {
            a0 += __shfl_xor(a0, m, 64);
            a1 += __shfl_xor(a1, m, 64);
            a2 += __shfl_xor(a2, m, 64);
            a3 += __shfl_xor(a3, m, 64);
        }

        if (lane < 4) {
            float dv = dinv[node];
            float4 bv = *reinterpret_cast<const float4*>(conv_b + slice * 16 + lane * 4);
            float o0 = fmaxf(a0 * dv + bv.x, 0.f);
            float o1 = fmaxf(a1 * dv + bv.y, 0.f);
            float o2 = fmaxf(a2 * dv + bv.z, 0.f);
            float o3 = fmaxf(a3 * dv + bv.w, 0.f);
            uint2 pk;
            pk.x = (unsigned)f2b(o0) | ((unsigned)f2b(o1) << 16);
            pk.y = (unsigned)f2b(o2) | ((unsigned)f2b(o3) << 16);
            *reinterpret_cast<uint2*>(h0 + (size_t)node * CIN + slice * 16 + lane * 4) = pk;
        }
    }
}

// ---------------- fused MLP v5: residual add folded into phase-1 A load ----

__device__ __forceinline__ short8 addres(short8 h, const float* __restrict__ px) {
    float4 f0 = *reinterpret_cast<const float4*>(px);
    float4 f1 = *reinterpret_cast<const float4*>(px + 4);
    short8 o;
    o[0] = (short)f2b(b2f((unsigned short)h[0]) + f0.x);
    o[1] = (short)f2b(b2f((unsigned short)h[1]) + f0.y);
    o[2] = (short)f2b(b2f((unsigned short)h[2]) + f0.z);
    o[3] = (short)f2b(b2f((unsigned short)h[3]) + f0.w);
    o[4] = (short)f2b(b2f((unsigned short)h[4]) + f1.x);
    o[5] = (short)f2b(b2f((unsigned short)h[5]) + f1.y);
    o[6] = (short)f2b(b2f((unsigned short)h[6]) + f1.z);
    o[7] = (short)f2b(b2f((unsigned short)h[7]) + f1.w);
    return o;
}

__global__ __launch_bounds__(256) void fmlp_k(
    const unsigned short* __restrict__ h0, const float* __restrict__ xres,
    const unsigned short* __restrict__ w1,
    const float* __restrict__ b1, const unsigned short* __restrict__ w2,
    const float* __restrict__ b2, const float* __restrict__ w3,
    float* __restrict__ rowsum, int M)
{
    __shared__ unsigned short h1s[64 * 256];   // 32 KB, xor-swizzled
    const int tid = threadIdx.x;
    const int wave = tid >> 6;
    const int lane = tid & 63;
    const int quad = lane >> 4;
    const int l16 = lane & 15;
    const int bm = blockIdx.x * 64;
    const int nc0 = wave * 64;

    f32x4 acc[4][4];
#pragma unroll
    for (int i = 0; i < 4; ++i)
#pragma unroll
        for (int j = 0; j < 4; ++j) {
            f32x4 z = {0.f, 0.f, 0.f, 0.f};
            acc[i][j] = z;
        }

    // ---- phase 1: h1 = relu((h0 + x) @ W1^T + b1), K=128 ----
    {
        const unsigned short* pa[4];
        const float* px[4];
        const unsigned short* pb[4];
#pragma unroll
        for (int t = 0; t < 4; ++t) {
            int m = bm + t * 16 + l16; if (m >= M) m = M - 1;
            pa[t] = h0 + (size_t)m * 128 + quad * 8;
            px[t] = xres + (size_t)m * 128 + quad * 8;
            int n = nc0 + t * 16 + l16;
            pb[t] = w1 + (size_t)n * 128 + quad * 8;
        }
        short8 af[2][4], bf[2][4];
#pragma unroll
        for (int t = 0; t < 4; ++t) {
            af[0][t] = addres(*reinterpret_cast<const short8*>(pa[t]), px[t]);
            bf[0][t] = *reinterpret_cast<const short8*>(pb[t]);
        }
#pragma unroll
        for (int kt = 0; kt < 4; ++kt) {
            const int cur = kt & 1, nxt = cur ^ 1;
            if (kt < 3) {
#pragma unroll
                for (int t = 0; t < 4; ++t) {
                    af[nxt][t] = addres(*reinterpret_cast<const short8*>(pa[t] + (kt + 1) * 32),
                                        px[t] + (kt + 1) * 32);
                    bf[nxt][t] = *reinterpret_cast<const short8*>(pb[t] + (kt + 1) * 32);
                }
            }
#pragma unroll
            for (int i = 0; i < 4; ++i)
#pragma unroll
                for (int j = 0; j < 4; ++j)
                    acc[i][j] = __builtin_amdgcn_mfma_f32_16x16x32_bf16(af[cur][i], bf[cur][j], acc[i][j], 0, 0, 0);
        }
        // relu+bias -> swizzled LDS: (row,col) at row*256 + (((col>>3)^(row&7))<<3 | (col&7))
#pragma unroll
        for (int nt = 0; nt < 4; ++nt) {
            int col = nc0 + nt * 16 + l16;
            float bv = b1[col];
            int chunk = col >> 3, rem = col & 7;
#pragma unroll
            for (int mt = 0; mt < 4; ++mt)
#pragma unroll
                for (int r = 0; r < 4; ++r) {
                    int row = mt * 16 + quad * 4 + r;
                    h1s[row * 256 + (((chunk ^ (row & 7)) << 3) | rem)] =
                        f2b(fmaxf(acc[mt][nt][r] + bv, 0.f));
                }
        }
    }
    __syncthreads();

    // ---- phase 2: h2 = relu(h1s @ W2^T + b2), K=256, ring-3 both streams ----
#pragma unroll
    for (int i = 0; i < 4; ++i)
#pragma unroll
        for (int j = 0; j < 4; ++j) {
            f32x4 z = {0.f, 0.f, 0.f, 0.f};
            acc[i][j] = z;
        }
    {
        const unsigned short* pb[4];
#pragma unroll
        for (int t = 0; t < 4; ++t) {
            int n = nc0 + t * 16 + l16;
            pb[t] = w2 + (size_t)n * 256 + quad * 8;
        }
        short8 af[3][4], bf[3][4];
#pragma unroll
        for (int t = 0; t < 4; ++t) {
            int row = t * 16 + l16;
            af[0][t] = *reinterpret_cast<const short8*>(
                &h1s[row * 256 + ((quad ^ (row & 7)) << 3)]);
            af[1][t] = *reinterpret_cast<const short8*>(
                &h1s[row * 256 + (((4 + quad) ^ (row & 7)) << 3)]);
            bf[0][t] = *reinterpret_cast<const short8*>(pb[t]);
            bf[1][t] = *reinterpret_cast<const short8*>(pb[t] + 32);
        }
#pragma unroll
        for (int kt = 0; kt < 8; ++kt) {
            const int cu = kt % 3, nx = (kt + 2) % 3;
            if (kt + 2 < 8) {
                const int c2 = (kt + 2) * 4 + quad;
#pragma unroll
                for (int t = 0; t < 4; ++t) {
                    int row = t * 16 + l16;
                    af[nx][t] = *reinterpret_cast<const short8*>(
                        &h1s[row * 256 + ((c2 ^ (row & 7)) << 3)]);
                    bf[nx][t] = *reinterpret_cast<const short8*>(pb[t] + (kt + 2) * 32);
                }
            }
#pragma unroll
            for (int i = 0; i < 4; ++i)
#pragma unroll
                for (int j = 0; j < 4; ++j)
                    acc[i][j] = __builtin_amdgcn_mfma_f32_16x16x32_bf16(af[cu][i], bf[cu][j], acc[i][j], 0, 0, 0);
        }
    }

    // ---- fused epilogue: partial w3-dot over this wave's 64 cols ----
    float part[4][4];
#pragma unroll
    for (int mt = 0; mt < 4; ++mt)
#pragma unroll
        for (int r = 0; r < 4; ++r) part[mt][r] = 0.f;
#pragma unroll
    for (int nt = 0; nt < 4; ++nt) {
        int col = nc0 + nt * 16 + l16;
        float bs = b2[col];
        float wv3 = w3[col];
#pragma unroll
        for (int mt = 0; mt < 4; ++mt)
#pragma unroll
            for (int r = 0; r < 4; ++r)
                part[mt][r] += fmaxf(acc[mt][nt][r] + bs, 0.f) * wv3;
    }
#pragma unroll
    for (int mt = 0; mt < 4; ++mt)
#pragma unroll
        for (int r = 0; r < 4; ++r) {
            float v = part[mt][r];
            v += __shfl_xor(v, 1, 64);
            v += __shfl_xor(v, 2, 64);
            v += __shfl_xor(v, 4, 64);
            v += __shfl_xor(v, 8, 64);
            part[mt][r] = v;
        }
    if (l16 == 0) {
#pragma unroll
        for (int mt = 0; mt < 4; ++mt)
#pragma unroll
            for (int r = 0; r < 4; ++r) {
                int row = bm + mt * 16 + quad * 4 + r;
                if (row < M) rowsum[(size_t)row * 4 + wave] = part[mt][r];
            }
    }
}

// ---------------- final: out[g] = b3 + sum of 80 rowsum slots ----------------

__global__ __launch_bounds__(256) void final_k(
    const float* __restrict__ rowsum, const float* __restrict__ b3,
    float* __restrict__ out)
{
    int g = blockIdx.x * 256 + threadIdx.x;
    if (g >= NGRAPH) return;
    const float4* p = reinterpret_cast<const float4*>(rowsum + (size_t)g * 80);
    float s = 0.f;
#pragma unroll
    for (int i = 0; i < 20; ++i) {
        float4 v = p[i];
        s += (v.x + v.y) + (v.z + v.w);
    }
    out[g] = s + b3[0];
}

// ---------------- launch ----------------

extern "C" void kernel_launch(void* const* d_in, const int* in_sizes, int n_in,
                              void* d_out, int out_size, void* d_ws, size_t ws_size,
                              hipStream_t stream)
{
    const float* x      = (const float*)d_in[0];
    const int*   ei     = (const int*)  d_in[1];
    const float* conv_w = (const float*)d_in[2];
    const float* conv_b = (const float*)d_in[3];
    const float* lin1_w = (const float*)d_in[4];
    const float* lin1_b = (const float*)d_in[5];
    const float* lin2_w = (const float*)d_in[6];
    const float* lin2_b = (const float*)d_in[7];
    const float* lin3_w = (const float*)d_in[8];
    const float* lin3_b = (const float*)d_in[9];
    float* out = (float*)d_out;

    // Workspace (~81 MB):
    //   xws bf16 [8 planes x N*16] | h0 bf16 [N*128] | entries u32 [NB*CAP] | csr
    //   rowptr2 int2 [N] | dinv [N] | bfill [NB] | wt0/wt1/wt2 | rowsum [100096*4]
    unsigned short* xws     = (unsigned short*)d_ws;
    unsigned short* h0      = xws + (size_t)12800000;
    unsigned*       entries = (unsigned*)(h0 + (size_t)12800000);
    int*            csr     = (int*)(entries + (size_t)NB * CAP);
    int2*           rowptr2 = (int2*)(csr + (size_t)NB * CAP);
    float*          dinv    = (float*)(rowptr2 + NNODES);
    int*            bfill   = (int*)(dinv + NNODES);
    unsigned short* wt0     = (unsigned short*)(bfill + NB + 8);
    unsigned short* wt1     = wt0 + 16384;
    unsigned short* wt2     = wt1 + 32768;
    float*          rowsum  = (float*)(wt2 + 65536);

    // CSR build (fixed-capacity bucket windows)
    hipMemsetAsync(bfill, 0, NB * sizeof(int), stream);
    bin_k<<<BIN_WGS, 256, 0, stream>>>(ei, bfill, entries);
    bucket_build_k<<<NB, 256, 0, stream>>>(entries, bfill, rowptr2, csr, dinv);

    // weight conversions (one launch)
    cvt_w_k<<<(114688 + 255) / 256, 256, 0, stream>>>(conv_w, lin1_w, lin2_w, wt0, wt1, wt2);

    // gemm0: xws = (x @ conv_w) * dinv[row], plane-sliced layout
    mgemm0_k<<<(NNODES + 127) / 128, 256, 0, stream>>>(x, wt0, dinv, xws, NNODES);

    // gather + conv epilogue -> h0 bf16 (XCD-sliced: 8 blocks of 32 nodes each,
    // slice = blockIdx & 7 pins each xws plane to one XCD's L2)
    gather_k<<<(NNODES / 32) * NSLICE, 256, 0, stream>>>(rowptr2, csr, xws, dinv, conv_b, h0);

    // fused MLP: residual add + gemm1 -> LDS -> gemm2 -> w3-dot -> rowsum
    fmlp_k<<<(NNODES + 63) / 64, 256, 0, stream>>>(h0, x, wt1, lin1_b, wt2, lin2_b, lin3_w,
                                                   rowsum, NNODES);

    // out[g] = b3 + sum of this graph's 80 rowsum slots
    final_k<<<(NGRAPH + 255) / 256, 256, 0, stream>>>(rowsum, lin3_b, out);
}

// Round 2
// 356.595 us; speedup vs baseline: 1.2791x; 1.2791x over previous
//
#include <hip/hip_runtime.h>
#include <hip/hip_bf16.h>
#include <cstddef>

#define NNODES 100000
#define NEDGES 1600000
#define CIN 128
#define HID 256
#define ACT 20
#define NGRAPH (NNODES / ACT)
#define BSHIFT 8
#define NB ((NNODES + 255) >> 8)     // 391 buckets of 256 nodes
#define BIN_WGS 512
#define PER_WG (NEDGES / BIN_WGS)    // 3125
#define CAP 8192                     // bucket window capacity (mean fill 4096)
#define NSLICE 8
#define PLANE ((size_t)NNODES * 16)  // elements per channel-plane (xws AND h0)

typedef __attribute__((ext_vector_type(8))) short short8;
typedef __attribute__((ext_vector_type(4))) float f32x4;

__device__ __forceinline__ unsigned short f2b(float f) {
    unsigned u = __float_as_uint(f);
    u += 0x7FFF + ((u >> 16) & 1);          // round-to-nearest-even
    return (unsigned short)(u >> 16);
}
__device__ __forceinline__ float b2f(unsigned short h) {
    return __uint_as_float(((unsigned)h) << 16);
}

// ---------------- bucketed CSR build (fixed-capacity windows) ----------------

__global__ __launch_bounds__(256) void bin_k(const int* __restrict__ ei,
                                             int* __restrict__ bfill,
                                             unsigned* __restrict__ entries) {
    __shared__ int cnt[NB], lofs[NB], base[NB], cur[NB];
    __shared__ unsigned lbuf[PER_WG];
    __shared__ int gdst[PER_WG];
    __shared__ int wsum[4];
    const int t = threadIdx.x;
    for (int i = t; i < NB; i += 256) { cnt[i] = 0; cur[i] = 0; }
    __syncthreads();
    const int s = blockIdx.x * PER_WG;
    const int e = s + PER_WG;
    for (int i = s + t; i < e; i += 256)
        atomicAdd(&cnt[ei[NEDGES + i] >> BSHIFT], 1);
    __syncthreads();
    int c0 = (2 * t < NB) ? cnt[2 * t] : 0;
    int c1 = (2 * t + 1 < NB) ? cnt[2 * t + 1] : 0;
    int v = c0 + c1;
    int lane = t & 63, wid = t >> 6;
    int inc = v;
#pragma unroll
    for (int o = 1; o < 64; o <<= 1) {
        int tv = __shfl_up(inc, o, 64);
        if (lane >= o) inc += tv;
    }
    if (lane == 63) wsum[wid] = inc;
    __syncthreads();
    int woff = 0;
#pragma unroll
    for (int w = 0; w < 4; ++w) woff += (w < wid) ? wsum[w] : 0;
    int excl = inc + woff - v;
    if (2 * t < NB) lofs[2 * t] = excl;
    if (2 * t + 1 < NB) lofs[2 * t + 1] = excl + c0;
    __syncthreads();
    for (int b = t; b < NB; b += 256)
        base[b] = cnt[b] ? atomicAdd(&bfill[b], cnt[b]) : 0;
    __syncthreads();
    for (int i = s + t; i < e; i += 256) {
        int src = ei[i], dst = ei[NEDGES + i];
        int b = dst >> BSHIFT;
        int r = atomicAdd(&cur[b], 1);
        int slot = lofs[b] + r;
        lbuf[slot] = ((unsigned)src << 8) | (unsigned)(dst & 255);
        int g = base[b] + r;
        gdst[slot] = (g < CAP) ? (int)((size_t)b * CAP + g) : -1;
    }
    __syncthreads();
    for (int i = t; i < PER_WG; i += 256) {
        int g = gdst[i];
        if (g >= 0) entries[g] = lbuf[i];
    }
}

__global__ __launch_bounds__(256) void bucket_build_k(
    const unsigned* __restrict__ entries, const int* __restrict__ bfill,
    int2* __restrict__ rowptr2, int* __restrict__ csr, float* __restrict__ dinv) {
    const int b = blockIdx.x;
    const int count = min(bfill[b], CAP);
    const int node0 = b << BSHIFT;
    const int nn = min(256, NNODES - node0);
    const size_t gbase = (size_t)b * CAP;
    __shared__ int cnt[256], off[256], cur[256];
    const int t = threadIdx.x;
    cnt[t] = 0; cur[t] = 0;
    __syncthreads();
    for (int i = t; i < count; i += 256)
        atomicAdd(&cnt[entries[gbase + i] & 255], 1);
    __syncthreads();
    int lane = t & 63, wid = t >> 6;
    int v = cnt[t];
    int inc = v;
#pragma unroll
    for (int o = 1; o < 64; o <<= 1) {
        int tv = __shfl_up(inc, o, 64);
        if (lane >= o) inc += tv;
    }
    __shared__ int wsum[4];
    if (lane == 63) wsum[wid] = inc;
    __syncthreads();
    int woff = 0;
#pragma unroll
    for (int w = 0; w < 4; ++w) woff += (w < wid) ? wsum[w] : 0;
    int excl = inc + woff - v;
    off[t] = excl;
    if (t < nn) {
        rowptr2[node0 + t] = make_int2((int)gbase + excl, (int)gbase + excl + v);
        dinv[node0 + t] = rsqrtf(1.0f + (float)v);
    }
    __syncthreads();
    for (int i = t; i < count; i += 256) {
        unsigned en = entries[gbase + i];
        int loc = (int)(en & 255);
        int r = atomicAdd(&cur[loc], 1);
        csr[gbase + off[loc] + r] = (int)(en >> 8);
    }
}

// ---------------- weight conversions (single launch) ----------------

__global__ void cvt_w_k(const float* __restrict__ conv_w,
                        const float* __restrict__ lin1_w,
                        const float* __restrict__ lin2_w,
                        unsigned short* __restrict__ wt0,
                        unsigned short* __restrict__ wt1,
                        unsigned short* __restrict__ wt2) {
    int id = blockIdx.x * 256 + threadIdx.x;
    if (id < 16384) {
        int k = id >> 7, n = id & 127;
        wt0[n * 128 + k] = f2b(conv_w[k * 128 + n]);
    } else if (id < 16384 + 32768) {
        int i = id - 16384;
        wt1[i] = f2b(lin1_w[i]);
    } else if (id < 16384 + 32768 + 65536) {
        int i = id - 49152;
        wt2[i] = f2b(lin2_w[i]);
    }
}

// ---------------- MFMA bf16 GEMM for conv (fp32 A, reg-pipelined) ----------
// C-write goes to the PLANE-SLICED xws layout:
//   plane p = channels [16p, 16p+16): xws[p*PLANE + row*16 + c]

__global__ __launch_bounds__(256) void mgemm0_k(
    const float* __restrict__ Af, const unsigned short* __restrict__ B,
    const float* __restrict__ dinv, unsigned short* __restrict__ Cout, int M)
{
    const int tid = threadIdx.x;
    const int wid = tid >> 6;
    const int lane = tid & 63;
    const int quad = lane >> 4;
    const int l16 = lane & 15;
    const int bm = blockIdx.x * 128 + (wid >> 1) * 64;
    const int bn = (wid & 1) * 64;

    const float* pa[4];
    const unsigned short* pb[4];
#pragma unroll
    for (int t = 0; t < 4; ++t) {
        int m = bm + t * 16 + l16; if (m >= M) m = M - 1;   // clamp; store guarded
        pa[t] = Af + (size_t)m * 128 + quad * 8;
        int n = bn + t * 16 + l16;
        pb[t] = B + (size_t)n * 128 + quad * 8;
    }

    f32x4 acc[4][4];
#pragma unroll
    for (int i = 0; i < 4; ++i)
#pragma unroll
        for (int j = 0; j < 4; ++j) {
            f32x4 z = {0.f, 0.f, 0.f, 0.f};
            acc[i][j] = z;
        }

    float4 afl[2][4][2];
    short8 bf[2][4];
#pragma unroll
    for (int t = 0; t < 4; ++t) {
        afl[0][t][0] = *reinterpret_cast<const float4*>(pa[t]);
        afl[0][t][1] = *reinterpret_cast<const float4*>(pa[t] + 4);
        bf[0][t] = *reinterpret_cast<const short8*>(pb[t]);
    }

#pragma unroll
    for (int kt = 0; kt < 4; ++kt) {
        const int cur = kt & 1, nxt = cur ^ 1;
        if (kt < 3) {
#pragma unroll
            for (int t = 0; t < 4; ++t) {
                afl[nxt][t][0] = *reinterpret_cast<const float4*>(pa[t] + (kt + 1) * 32);
                afl[nxt][t][1] = *reinterpret_cast<const float4*>(pa[t] + (kt + 1) * 32 + 4);
                bf[nxt][t] = *reinterpret_cast<const short8*>(pb[t] + (kt + 1) * 32);
            }
        }
        short8 a[4];
#pragma unroll
        for (int t = 0; t < 4; ++t) {
            float4 f0 = afl[cur][t][0], f1 = afl[cur][t][1];
            short8 av;
            av[0] = (short)f2b(f0.x); av[1] = (short)f2b(f0.y);
            av[2] = (short)f2b(f0.z); av[3] = (short)f2b(f0.w);
            av[4] = (short)f2b(f1.x); av[5] = (short)f2b(f1.y);
            av[6] = (short)f2b(f1.z); av[7] = (short)f2b(f1.w);
            a[t] = av;
        }
#pragma unroll
        for (int i = 0; i < 4; ++i)
#pragma unroll
            for (int j = 0; j < 4; ++j)
                acc[i][j] = __builtin_amdgcn_mfma_f32_16x16x32_bf16(a[i], bf[cur][j], acc[i][j], 0, 0, 0);
    }

#pragma unroll
    for (int i = 0; i < 4; ++i)
#pragma unroll
        for (int r = 0; r < 4; ++r) {
            int row = bm + i * 16 + quad * 4 + r;
            if (row >= M) continue;
            float dv = dinv[row];
#pragma unroll
            for (int j = 0; j < 4; ++j) {
                // col = bn + j*16 + l16; plane = (bn>>4)+j; within = l16
                size_t pbase = (size_t)((bn >> 4) + j) * PLANE;
                Cout[pbase + (size_t)row * 16 + l16] = f2b(acc[i][j][r] * dv);
            }
        }
}

// ---------------- gather v7: XCD-sliced, 4-lane group per node ----------------
// slice = blockIdx & 7 pins each 3.2 MB xws plane to one XCD's L2 (proven by
// round-1 FETCH drop 219->89 MB). Each 4-lane group owns ONE node: lane owns
// 4 channels, accumulates in registers over the node's edges (8-deep unrolled
// 8-B gathers, no cross-lane reduce). 16 nodes/wave, 64/block. h0 is ALSO
// plane-sliced -> stores are 512 B contiguous per wave, no cross-XCD lines.

__global__ __launch_bounds__(256) void gather_k(
    const int2* __restrict__ rowptr2, const int* __restrict__ csr,
    const unsigned short* __restrict__ xws, const float* __restrict__ dinv,
    const float* __restrict__ conv_b, unsigned short* __restrict__ h0)
{
    const int slice = blockIdx.x & 7;
    const int ng = blockIdx.x >> 3;
    const int lane = threadIdx.x & 63;
    const int wave = threadIdx.x >> 6;
    const int node = ng * 64 + wave * 16 + (lane >> 2);
    const int cq = lane & 3;
    if (node >= NNODES) return;
    const unsigned short* xp = xws + (size_t)slice * PLANE;

    const int2 se = rowptr2[node];
    const int start = se.x, end = se.y;

    // self-loop contribution
    uint2 sv = *reinterpret_cast<const uint2*>(xp + (size_t)node * 16 + cq * 4);
    float a0 = __uint_as_float(sv.x << 16);
    float a1 = __uint_as_float(sv.x & 0xffff0000u);
    float a2 = __uint_as_float(sv.y << 16);
    float a3 = __uint_as_float(sv.y & 0xffff0000u);

    for (int e = start; e < end; e += 8) {
        uint2 r[8];
        int val[8];
#pragma unroll
        for (int u = 0; u < 8; ++u) {
            int ee = e + u;
            bool ok = ee < end;
            int idx = ok ? csr[ee] : node;
            r[u] = *reinterpret_cast<const uint2*>(xp + (size_t)idx * 16 + cq * 4);
            val[u] = ok;
        }
#pragma unroll
        for (int u = 0; u < 8; ++u)
            if (val[u]) {
                a0 += __uint_as_float(r[u].x << 16);
                a1 += __uint_as_float(r[u].x & 0xffff0000u);
                a2 += __uint_as_float(r[u].y << 16);
                a3 += __uint_as_float(r[u].y & 0xffff0000u);
            }
    }

    const float dv = dinv[node];
    const float4 bv = *reinterpret_cast<const float4*>(conv_b + slice * 16 + cq * 4);
    uint2 pk;
    pk.x = (unsigned)f2b(fmaxf(a0 * dv + bv.x, 0.f)) |
           ((unsigned)f2b(fmaxf(a1 * dv + bv.y, 0.f)) << 16);
    pk.y = (unsigned)f2b(fmaxf(a2 * dv + bv.z, 0.f)) |
           ((unsigned)f2b(fmaxf(a3 * dv + bv.w, 0.f)) << 16);
    *reinterpret_cast<uint2*>(h0 + (size_t)slice * PLANE + (size_t)node * 16 + cq * 4) = pk;
}

// ---------------- fused MLP v6: plane-sliced h0 A-load + residual fold ----

__device__ __forceinline__ short8 addres(short8 h, const float* __restrict__ px) {
    float4 f0 = *reinterpret_cast<const float4*>(px);
    float4 f1 = *reinterpret_cast<const float4*>(px + 4);
    short8 o;
    o[0] = (short)f2b(b2f((unsigned short)h[0]) + f0.x);
    o[1] = (short)f2b(b2f((unsigned short)h[1]) + f0.y);
    o[2] = (short)f2b(b2f((unsigned short)h[2]) + f0.z);
    o[3] = (short)f2b(b2f((unsigned short)h[3]) + f0.w);
    o[4] = (short)f2b(b2f((unsigned short)h[4]) + f1.x);
    o[5] = (short)f2b(b2f((unsigned short)h[5]) + f1.y);
    o[6] = (short)f2b(b2f((unsigned short)h[6]) + f1.z);
    o[7] = (short)f2b(b2f((unsigned short)h[7]) + f1.w);
    return o;
}

__global__ __launch_bounds__(256) void fmlp_k(
    const unsigned short* __restrict__ h0, const float* __restrict__ xres,
    const unsigned short* __restrict__ w1,
    const float* __restrict__ b1, const unsigned short* __restrict__ w2,
    const float* __restrict__ b2, const float* __restrict__ w3,
    float* __restrict__ rowsum, int M)
{
    __shared__ unsigned short h1s[64 * 256];   // 32 KB, xor-swizzled
    const int tid = threadIdx.x;
    const int wave = tid >> 6;
    const int lane = tid & 63;
    const int quad = lane >> 4;
    const int l16 = lane & 15;
    const int bm = blockIdx.x * 64;
    const int nc0 = wave * 64;

    f32x4 acc[4][4];
#pragma unroll
    for (int i = 0; i < 4; ++i)
#pragma unroll
        for (int j = 0; j < 4; ++j) {
            f32x4 z = {0.f, 0.f, 0.f, 0.f};
            acc[i][j] = z;
        }

    // ---- phase 1: h1 = relu((h0 + x) @ W1^T + b1), K=128 ----
    // h0 is plane-sliced: ch = kt*32 + quad*8 -> plane = 2*kt + (quad>>1),
    // within-plane offset = (quad&1)*8. A-load step per kt = 2*PLANE.
    {
        const unsigned short* pa[4];
        const float* px[4];
        const unsigned short* pb[4];
#pragma unroll
        for (int t = 0; t < 4; ++t) {
            int m = bm + t * 16 + l16; if (m >= M) m = M - 1;
            pa[t] = h0 + ((size_t)(quad >> 1)) * PLANE + (size_t)m * 16 + (quad & 1) * 8;
            px[t] = xres + (size_t)m * 128 + quad * 8;
            int n = nc0 + t * 16 + l16;
            pb[t] = w1 + (size_t)n * 128 + quad * 8;
        }
        short8 af[2][4], bf[2][4];
#pragma unroll
        for (int t = 0; t < 4; ++t) {
            af[0][t] = addres(*reinterpret_cast<const short8*>(pa[t]), px[t]);
            bf[0][t] = *reinterpret_cast<const short8*>(pb[t]);
        }
#pragma unroll
        for (int kt = 0; kt < 4; ++kt) {
            const int cur = kt & 1, nxt = cur ^ 1;
            if (kt < 3) {
#pragma unroll
                for (int t = 0; t < 4; ++t) {
                    af[nxt][t] = addres(*reinterpret_cast<const short8*>(
                                            pa[t] + (size_t)(kt + 1) * 2 * PLANE),
                                        px[t] + (kt + 1) * 32);
                    bf[nxt][t] = *reinterpret_cast<const short8*>(pb[t] + (kt + 1) * 32);
                }
            }
#pragma unroll
            for (int i = 0; i < 4; ++i)
#pragma unroll
                for (int j = 0; j < 4; ++j)
                    acc[i][j] = __builtin_amdgcn_mfma_f32_16x16x32_bf16(af[cur][i], bf[cur][j], acc[i][j], 0, 0, 0);
        }
        // relu+bias -> swizzled LDS: (row,col) at row*256 + (((col>>3)^(row&7))<<3 | (col&7))
#pragma unroll
        for (int nt = 0; nt < 4; ++nt) {
            int col = nc0 + nt * 16 + l16;
            float bv = b1[col];
            int chunk = col >> 3, rem = col & 7;
#pragma unroll
            for (int mt = 0; mt < 4; ++mt)
#pragma unroll
                for (int r = 0; r < 4; ++r) {
                    int row = mt * 16 + quad * 4 + r;
                    h1s[row * 256 + (((chunk ^ (row & 7)) << 3) | rem)] =
                        f2b(fmaxf(acc[mt][nt][r] + bv, 0.f));
                }
        }
    }
    __syncthreads();

    // ---- phase 2: h2 = relu(h1s @ W2^T + b2), K=256, ring-3 both streams ----
#pragma unroll
    for (int i = 0; i < 4; ++i)
#pragma unroll
        for (int j = 0; j < 4; ++j) {
            f32x4 z = {0.f, 0.f, 0.f, 0.f};
            acc[i][j] = z;
        }
    {
        const unsigned short* pb[4];
#pragma unroll
        for (int t = 0; t < 4; ++t) {
            int n = nc0 + t * 16 + l16;
            pb[t] = w2 + (size_t)n * 256 + quad * 8;
        }
        short8 af[3][4], bf[3][4];
#pragma unroll
        for (int t = 0; t < 4; ++t) {
            int row = t * 16 + l16;
            af[0][t] = *reinterpret_cast<const short8*>(
                &h1s[row * 256 + ((quad ^ (row & 7)) << 3)]);
            af[1][t] = *reinterpret_cast<const short8*>(
                &h1s[row * 256 + (((4 + quad) ^ (row & 7)) << 3)]);
            bf[0][t] = *reinterpret_cast<const short8*>(pb[t]);
            bf[1][t] = *reinterpret_cast<const short8*>(pb[t] + 32);
        }
#pragma unroll
        for (int kt = 0; kt < 8; ++kt) {
            const int cu = kt % 3, nx = (kt + 2) % 3;
            if (kt + 2 < 8) {
                const int c2 = (kt + 2) * 4 + quad;
#pragma unroll
                for (int t = 0; t < 4; ++t) {
                    int row = t * 16 + l16;
                    af[nx][t] = *reinterpret_cast<const short8*>(
                        &h1s[row * 256 + ((c2 ^ (row & 7)) << 3)]);
                    bf[nx][t] = *reinterpret_cast<const short8*>(pb[t] + (kt + 2) * 32);
                }
            }
#pragma unroll
            for (int i = 0; i < 4; ++i)
#pragma unroll
                for (int j = 0; j < 4; ++j)
                    acc[i][j] = __builtin_amdgcn_mfma_f32_16x16x32_bf16(af[cu][i], bf[cu][j], acc[i][j], 0, 0, 0);
        }
    }

    // ---- fused epilogue: partial w3-dot over this wave's 64 cols ----
    float part[4][4];
#pragma unroll
    for (int mt = 0; mt < 4; ++mt)
#pragma unroll
        for (int r = 0; r < 4; ++r) part[mt][r] = 0.f;
#pragma unroll
    for (int nt = 0; nt < 4; ++nt) {
        int col = nc0 + nt * 16 + l16;
        float bs = b2[col];
        float wv3 = w3[col];
#pragma unroll
        for (int mt = 0; mt < 4; ++mt)
#pragma unroll
            for (int r = 0; r < 4; ++r)
                part[mt][r] += fmaxf(acc[mt][nt][r] + bs, 0.f) * wv3;
    }
#pragma unroll
    for (int mt = 0; mt < 4; ++mt)
#pragma unroll
        for (int r = 0; r < 4; ++r) {
            float v = part[mt][r];
            v += __shfl_xor(v, 1, 64);
            v += __shfl_xor(v, 2, 64);
            v += __shfl_xor(v, 4, 64);
            v += __shfl_xor(v, 8, 64);
            part[mt][r] = v;
        }
    if (l16 == 0) {
#pragma unroll
        for (int mt = 0; mt < 4; ++mt)
#pragma unroll
            for (int r = 0; r < 4; ++r) {
                int row = bm + mt * 16 + quad * 4 + r;
                if (row < M) rowsum[(size_t)row * 4 + wave] = part[mt][r];
            }
    }
}

// ---------------- final: out[g] = b3 + sum of 80 rowsum slots ----------------

__global__ __launch_bounds__(256) void final_k(
    const float* __restrict__ rowsum, const float* __restrict__ b3,
    float* __restrict__ out)
{
    int g = blockIdx.x * 256 + threadIdx.x;
    if (g >= NGRAPH) return;
    const float4* p = reinterpret_cast<const float4*>(rowsum + (size_t)g * 80);
    float s = 0.f;
#pragma unroll
    for (int i = 0; i < 20; ++i) {
        float4 v = p[i];
        s += (v.x + v.y) + (v.z + v.w);
    }
    out[g] = s + b3[0];
}

// ---------------- launch ----------------

extern "C" void kernel_launch(void* const* d_in, const int* in_sizes, int n_in,
                              void* d_out, int out_size, void* d_ws, size_t ws_size,
                              hipStream_t stream)
{
    const float* x      = (const float*)d_in[0];
    const int*   ei     = (const int*)  d_in[1];
    const float* conv_w = (const float*)d_in[2];
    const float* conv_b = (const float*)d_in[3];
    const float* lin1_w = (const float*)d_in[4];
    const float* lin1_b = (const float*)d_in[5];
    const float* lin2_w = (const float*)d_in[6];
    const float* lin2_b = (const float*)d_in[7];
    const float* lin3_w = (const float*)d_in[8];
    const float* lin3_b = (const float*)d_in[9];
    float* out = (float*)d_out;

    // Workspace (~81 MB):
    //   xws bf16 [8 planes x N*16] | h0 bf16 [8 planes x N*16] | entries | csr
    //   rowptr2 int2 [N] | dinv [N] | bfill [NB] | wt0/wt1/wt2 | rowsum
    unsigned short* xws     = (unsigned short*)d_ws;
    unsigned short* h0      = xws + (size_t)12800000;
    unsigned*       entries = (unsigned*)(h0 + (size_t)12800000);
    int*            csr     = (int*)(entries + (size_t)NB * CAP);
    int2*           rowptr2 = (int2*)(csr + (size_t)NB * CAP);
    float*          dinv    = (float*)(rowptr2 + NNODES);
    int*            bfill   = (int*)(dinv + NNODES);
    unsigned short* wt0     = (unsigned short*)(bfill + NB + 8);
    unsigned short* wt1     = wt0 + 16384;
    unsigned short* wt2     = wt1 + 32768;
    float*          rowsum  = (float*)(wt2 + 65536);

    // CSR build (fixed-capacity bucket windows)
    hipMemsetAsync(bfill, 0, NB * sizeof(int), stream);
    bin_k<<<BIN_WGS, 256, 0, stream>>>(ei, bfill, entries);
    bucket_build_k<<<NB, 256, 0, stream>>>(entries, bfill, rowptr2, csr, dinv);

    // weight conversions (one launch)
    cvt_w_k<<<(114688 + 255) / 256, 256, 0, stream>>>(conv_w, lin1_w, lin2_w, wt0, wt1, wt2);

    // gemm0: xws = (x @ conv_w) * dinv[row], plane-sliced layout
    mgemm0_k<<<(NNODES + 127) / 128, 256, 0, stream>>>(x, wt0, dinv, xws, NNODES);

    // gather + conv epilogue -> h0 (plane-sliced). 4-lane group per node,
    // slice = blockIdx & 7 pins each plane to one XCD's L2.
    gather_k<<<((NNODES + 63) / 64) * NSLICE, 256, 0, stream>>>(rowptr2, csr, xws, dinv,
                                                                conv_b, h0);

    // fused MLP: residual add + gemm1 -> LDS -> gemm2 -> w3-dot -> rowsum
    fmlp_k<<<(NNODES + 63) / 64, 256, 0, stream>>>(h0, x, wt1, lin1_b, wt2, lin2_b, lin3_w,
                                                   rowsum, NNODES);

    // out[g] = b3 + sum of this graph's 80 rowsum slots
    final_k<<<(NGRAPH + 255) / 256, 256, 0, stream>>>(rowsum, lin3_b, out);
}

// Round 3
// 330.664 us; speedup vs baseline: 1.3794x; 1.0784x over previous
//
#include <hip/hip_runtime.h>
#include <hip/hip_bf16.h>
#include <cstddef>

#define NNODES 100000
#define NEDGES 1600000
#define CIN 128
#define HID 256
#define ACT 20
#define NGRAPH (NNODES / ACT)
#define BSHIFT 8
#define NB ((NNODES + 255) >> 8)     // 391 buckets of 256 nodes
#define BIN_WGS 512
#define PER_WG (NEDGES / BIN_WGS)    // 3125
#define CAP 8192                     // bucket window capacity (mean fill 4096)
#define NSLICE 8
#define PLANE ((size_t)NNODES * 16)  // elements per channel-plane (xws AND h0)

typedef __attribute__((ext_vector_type(8))) short short8;
typedef __attribute__((ext_vector_type(4))) float f32x4;

__device__ __forceinline__ unsigned short f2b(float f) {
    unsigned u = __float_as_uint(f);
    u += 0x7FFF + ((u >> 16) & 1);          // round-to-nearest-even
    return (unsigned short)(u >> 16);
}
__device__ __forceinline__ float b2f(unsigned short h) {
    return __uint_as_float(((unsigned)h) << 16);
}

// ---------------- bucketed CSR build (fixed-capacity windows) ----------------

__global__ __launch_bounds__(256) void bin_k(const int* __restrict__ ei,
                                             int* __restrict__ bfill,
                                             unsigned* __restrict__ entries) {
    __shared__ int cnt[NB], lofs[NB], base[NB], cur[NB];
    __shared__ unsigned lbuf[PER_WG];
    __shared__ int gdst[PER_WG];
    __shared__ int wsum[4];
    const int t = threadIdx.x;
    for (int i = t; i < NB; i += 256) { cnt[i] = 0; cur[i] = 0; }
    __syncthreads();
    const int s = blockIdx.x * PER_WG;
    const int e = s + PER_WG;
    for (int i = s + t; i < e; i += 256)
        atomicAdd(&cnt[ei[NEDGES + i] >> BSHIFT], 1);
    __syncthreads();
    int c0 = (2 * t < NB) ? cnt[2 * t] : 0;
    int c1 = (2 * t + 1 < NB) ? cnt[2 * t + 1] : 0;
    int v = c0 + c1;
    int lane = t & 63, wid = t >> 6;
    int inc = v;
#pragma unroll
    for (int o = 1; o < 64; o <<= 1) {
        int tv = __shfl_up(inc, o, 64);
        if (lane >= o) inc += tv;
    }
    if (lane == 63) wsum[wid] = inc;
    __syncthreads();
    int woff = 0;
#pragma unroll
    for (int w = 0; w < 4; ++w) woff += (w < wid) ? wsum[w] : 0;
    int excl = inc + woff - v;
    if (2 * t < NB) lofs[2 * t] = excl;
    if (2 * t + 1 < NB) lofs[2 * t + 1] = excl + c0;
    __syncthreads();
    for (int b = t; b < NB; b += 256)
        base[b] = cnt[b] ? atomicAdd(&bfill[b], cnt[b]) : 0;
    __syncthreads();
    for (int i = s + t; i < e; i += 256) {
        int src = ei[i], dst = ei[NEDGES + i];
        int b = dst >> BSHIFT;
        int r = atomicAdd(&cur[b], 1);
        int slot = lofs[b] + r;
        lbuf[slot] = ((unsigned)src << 8) | (unsigned)(dst & 255);
        int g = base[b] + r;
        gdst[slot] = (g < CAP) ? (int)((size_t)b * CAP + g) : -1;
    }
    __syncthreads();
    for (int i = t; i < PER_WG; i += 256) {
        int g = gdst[i];
        if (g >= 0) entries[g] = lbuf[i];
    }
}

__global__ __launch_bounds__(256) void bucket_build_k(
    const unsigned* __restrict__ entries, const int* __restrict__ bfill,
    int2* __restrict__ rowptr2, int* __restrict__ csr, float* __restrict__ dinv) {
    const int b = blockIdx.x;
    const int count = min(bfill[b], CAP);
    const int node0 = b << BSHIFT;
    const int nn = min(256, NNODES - node0);
    const size_t gbase = (size_t)b * CAP;
    __shared__ int cnt[256], off[256], cur[256];
    const int t = threadIdx.x;
    cnt[t] = 0; cur[t] = 0;
    __syncthreads();
    for (int i = t; i < count; i += 256)
        atomicAdd(&cnt[entries[gbase + i] & 255], 1);
    __syncthreads();
    int lane = t & 63, wid = t >> 6;
    int v = cnt[t];
    int inc = v;
#pragma unroll
    for (int o = 1; o < 64; o <<= 1) {
        int tv = __shfl_up(inc, o, 64);
        if (lane >= o) inc += tv;
    }
    __shared__ int wsum[4];
    if (lane == 63) wsum[wid] = inc;
    __syncthreads();
    int woff = 0;
#pragma unroll
    for (int w = 0; w < 4; ++w) woff += (w < wid) ? wsum[w] : 0;
    int excl = inc + woff - v;
    off[t] = excl;
    if (t < nn) {
        rowptr2[node0 + t] = make_int2((int)gbase + excl, (int)gbase + excl + v);
        dinv[node0 + t] = rsqrtf(1.0f + (float)v);
    }
    __syncthreads();
    for (int i = t; i < count; i += 256) {
        unsigned en = entries[gbase + i];
        int loc = (int)(en & 255);
        int r = atomicAdd(&cur[loc], 1);
        csr[gbase + off[loc] + r] = (int)(en >> 8);
    }
}

// ---------------- weight conversions (single launch) ----------------

__global__ void cvt_w_k(const float* __restrict__ conv_w,
                        const float* __restrict__ lin1_w,
                        const float* __restrict__ lin2_w,
                        unsigned short* __restrict__ wt0,
                        unsigned short* __restrict__ wt1,
                        unsigned short* __restrict__ wt2) {
    int id = blockIdx.x * 256 + threadIdx.x;
    if (id < 16384) {
        int k = id >> 7, n = id & 127;
        wt0[n * 128 + k] = f2b(conv_w[k * 128 + n]);
    } else if (id < 16384 + 32768) {
        int i = id - 16384;
        wt1[i] = f2b(lin1_w[i]);
    } else if (id < 16384 + 32768 + 65536) {
        int i = id - 49152;
        wt2[i] = f2b(lin2_w[i]);
    }
}

// ---------------- MFMA bf16 GEMM for conv (fp32 A, reg-pipelined) ----------
// C-write goes to the PLANE-SLICED xws layout:
//   plane p = channels [16p, 16p+16): xws[p*PLANE + row*16 + c]

__global__ __launch_bounds__(256) void mgemm0_k(
    const float* __restrict__ Af, const unsigned short* __restrict__ B,
    const float* __restrict__ dinv, unsigned short* __restrict__ Cout, int M)
{
    const int tid = threadIdx.x;
    const int wid = tid >> 6;
    const int lane = tid & 63;
    const int quad = lane >> 4;
    const int l16 = lane & 15;
    const int bm = blockIdx.x * 128 + (wid >> 1) * 64;
    const int bn = (wid & 1) * 64;

    const float* pa[4];
    const unsigned short* pb[4];
#pragma unroll
    for (int t = 0; t < 4; ++t) {
        int m = bm + t * 16 + l16; if (m >= M) m = M - 1;   // clamp; store guarded
        pa[t] = Af + (size_t)m * 128 + quad * 8;
        int n = bn + t * 16 + l16;
        pb[t] = B + (size_t)n * 128 + quad * 8;
    }

    f32x4 acc[4][4];
#pragma unroll
    for (int i = 0; i < 4; ++i)
#pragma unroll
        for (int j = 0; j < 4; ++j) {
            f32x4 z = {0.f, 0.f, 0.f, 0.f};
            acc[i][j] = z;
        }

    float4 afl[2][4][2];
    short8 bf[2][4];
#pragma unroll
    for (int t = 0; t < 4; ++t) {
        afl[0][t][0] = *reinterpret_cast<const float4*>(pa[t]);
        afl[0][t][1] = *reinterpret_cast<const float4*>(pa[t] + 4);
        bf[0][t] = *reinterpret_cast<const short8*>(pb[t]);
    }

#pragma unroll
    for (int kt = 0; kt < 4; ++kt) {
        const int cur = kt & 1, nxt = cur ^ 1;
        if (kt < 3) {
#pragma unroll
            for (int t = 0; t < 4; ++t) {
                afl[nxt][t][0] = *reinterpret_cast<const float4*>(pa[t] + (kt + 1) * 32);
                afl[nxt][t][1] = *reinterpret_cast<const float4*>(pa[t] + (kt + 1) * 32 + 4);
                bf[nxt][t] = *reinterpret_cast<const short8*>(pb[t] + (kt + 1) * 32);
            }
        }
        short8 a[4];
#pragma unroll
        for (int t = 0; t < 4; ++t) {
            float4 f0 = afl[cur][t][0], f1 = afl[cur][t][1];
            short8 av;
            av[0] = (short)f2b(f0.x); av[1] = (short)f2b(f0.y);
            av[2] = (short)f2b(f0.z); av[3] = (short)f2b(f0.w);
            av[4] = (short)f2b(f1.x); av[5] = (short)f2b(f1.y);
            av[6] = (short)f2b(f1.z); av[7] = (short)f2b(f1.w);
            a[t] = av;
        }
#pragma unroll
        for (int i = 0; i < 4; ++i)
#pragma unroll
            for (int j = 0; j < 4; ++j)
                acc[i][j] = __builtin_amdgcn_mfma_f32_16x16x32_bf16(a[i], bf[cur][j], acc[i][j], 0, 0, 0);
    }

#pragma unroll
    for (int i = 0; i < 4; ++i)
#pragma unroll
        for (int r = 0; r < 4; ++r) {
            int row = bm + i * 16 + quad * 4 + r;
            if (row >= M) continue;
            float dv = dinv[row];
#pragma unroll
            for (int j = 0; j < 4; ++j) {
                // col = bn + j*16 + l16; plane = (bn>>4)+j; within = l16
                size_t pbase = (size_t)((bn >> 4) + j) * PLANE;
                Cout[pbase + (size_t)row * 16 + l16] = f2b(acc[i][j][r] * dv);
            }
        }
}

// ---------------- gather v8: line-touch-minimized XCD-sliced gather ----------
// 4-lane group per node. Per 4-edge step:
//   - all 4 lanes broadcast-load ONE uint4 of csr indices (0.25 line-touches
//     per edge-slice), software-pipelined one step ahead;
//   - 2 data instrs: lane pair (half=cq&1) loads the two 16B halves of one
//     edge's 32B row -> halves merge into one 64B line: 1 touch/edge-slice.
// Lane accumulates its 8-channel half; one shfl_xor(2) pair-reduce at end.

__global__ __launch_bounds__(256) void gather_k(
    const int2* __restrict__ rowptr2, const int* __restrict__ csr,
    const unsigned short* __restrict__ xws, const float* __restrict__ dinv,
    const float* __restrict__ conv_b, unsigned short* __restrict__ h0)
{
    const int slice = blockIdx.x & 7;
    const int ng = blockIdx.x >> 3;
    const int lane = threadIdx.x & 63;
    const int wave = threadIdx.x >> 6;
    const int node = ng * 64 + wave * 16 + (lane >> 2);
    const int cq = lane & 3;
    const int half = cq & 1;           // which 16B half-row this lane owns
    const int sel = cq >> 1;           // edge selector within a data instr
    if (node >= NNODES) return;
    const unsigned short* xp = xws + (size_t)slice * PLANE;

    const int2 se = rowptr2[node];
    const int start = se.x, end = se.y;

    float a[8];
    if (cq < 2) {   // self-loop: only the first lane-pair, to avoid double count
        uint4 v = *reinterpret_cast<const uint4*>(xp + (size_t)node * 16 + half * 8);
        a[0] = __uint_as_float(v.x << 16); a[1] = __uint_as_float(v.x & 0xffff0000u);
        a[2] = __uint_as_float(v.y << 16); a[3] = __uint_as_float(v.y & 0xffff0000u);
        a[4] = __uint_as_float(v.z << 16); a[5] = __uint_as_float(v.z & 0xffff0000u);
        a[6] = __uint_as_float(v.w << 16); a[7] = __uint_as_float(v.w & 0xffff0000u);
    } else {
#pragma unroll
        for (int i = 0; i < 8; ++i) a[i] = 0.f;
    }

    const int es = start & ~3;         // 16B-align the csr window
    uint4 nid = *reinterpret_cast<const uint4*>(csr + es);
    for (int e = es; e < end; e += 4) {
        const uint4 idx4 = nid;
        if (e + 4 < end) nid = *reinterpret_cast<const uint4*>(csr + e + 4);
        const int e0 = e + sel, e1 = e + 2 + sel;
        const bool ok0 = (e0 >= start) & (e0 < end);
        const bool ok1 = (e1 >= start) & (e1 < end);
        const int r0 = ok0 ? (sel ? (int)idx4.y : (int)idx4.x) : node;
        const int r1 = ok1 ? (sel ? (int)idx4.w : (int)idx4.z) : node;
        uint4 d0 = *reinterpret_cast<const uint4*>(xp + (size_t)r0 * 16 + half * 8);
        uint4 d1 = *reinterpret_cast<const uint4*>(xp + (size_t)r1 * 16 + half * 8);
        if (ok0) {
            a[0] += __uint_as_float(d0.x << 16); a[1] += __uint_as_float(d0.x & 0xffff0000u);
            a[2] += __uint_as_float(d0.y << 16); a[3] += __uint_as_float(d0.y & 0xffff0000u);
            a[4] += __uint_as_float(d0.z << 16); a[5] += __uint_as_float(d0.z & 0xffff0000u);
            a[6] += __uint_as_float(d0.w << 16); a[7] += __uint_as_float(d0.w & 0xffff0000u);
        }
        if (ok1) {
            a[0] += __uint_as_float(d1.x << 16); a[1] += __uint_as_float(d1.x & 0xffff0000u);
            a[2] += __uint_as_float(d1.y << 16); a[3] += __uint_as_float(d1.y & 0xffff0000u);
            a[4] += __uint_as_float(d1.z << 16); a[5] += __uint_as_float(d1.z & 0xffff0000u);
            a[6] += __uint_as_float(d1.w << 16); a[7] += __uint_as_float(d1.w & 0xffff0000u);
        }
    }

    // combine the two lane-pairs (lanes cq and cq^2 hold the same half)
#pragma unroll
    for (int i = 0; i < 8; ++i) a[i] += __shfl_xor(a[i], 2, 64);

    if (cq < 2) {
        const float dv = dinv[node];
        const float4 b0 = *reinterpret_cast<const float4*>(conv_b + slice * 16 + half * 8);
        const float4 b1 = *reinterpret_cast<const float4*>(conv_b + slice * 16 + half * 8 + 4);
        float o[8];
        o[0] = fmaxf(a[0] * dv + b0.x, 0.f);
        o[1] = fmaxf(a[1] * dv + b0.y, 0.f);
        o[2] = fmaxf(a[2] * dv + b0.z, 0.f);
        o[3] = fmaxf(a[3] * dv + b0.w, 0.f);
        o[4] = fmaxf(a[4] * dv + b1.x, 0.f);
        o[5] = fmaxf(a[5] * dv + b1.y, 0.f);
        o[6] = fmaxf(a[6] * dv + b1.z, 0.f);
        o[7] = fmaxf(a[7] * dv + b1.w, 0.f);
        uint4 pk;
        pk.x = (unsigned)f2b(o[0]) | ((unsigned)f2b(o[1]) << 16);
        pk.y = (unsigned)f2b(o[2]) | ((unsigned)f2b(o[3]) << 16);
        pk.z = (unsigned)f2b(o[4]) | ((unsigned)f2b(o[5]) << 16);
        pk.w = (unsigned)f2b(o[6]) | ((unsigned)f2b(o[7]) << 16);
        *reinterpret_cast<uint4*>(h0 + (size_t)slice * PLANE + (size_t)node * 16 + half * 8) = pk;
    }
}

// ---------------- fused MLP v6: plane-sliced h0 A-load + residual fold ----

__device__ __forceinline__ short8 addres(short8 h, const float* __restrict__ px) {
    float4 f0 = *reinterpret_cast<const float4*>(px);
    float4 f1 = *reinterpret_cast<const float4*>(px + 4);
    short8 o;
    o[0] = (short)f2b(b2f((unsigned short)h[0]) + f0.x);
    o[1] = (short)f2b(b2f((unsigned short)h[1]) + f0.y);
    o[2] = (short)f2b(b2f((unsigned short)h[2]) + f0.z);
    o[3] = (short)f2b(b2f((unsigned short)h[3]) + f0.w);
    o[4] = (short)f2b(b2f((unsigned short)h[4]) + f1.x);
    o[5] = (short)f2b(b2f((unsigned short)h[5]) + f1.y);
    o[6] = (short)f2b(b2f((unsigned short)h[6]) + f1.z);
    o[7] = (short)f2b(b2f((unsigned short)h[7]) + f1.w);
    return o;
}

__global__ __launch_bounds__(256) void fmlp_k(
    const unsigned short* __restrict__ h0, const float* __restrict__ xres,
    const unsigned short* __restrict__ w1,
    const float* __restrict__ b1, const unsigned short* __restrict__ w2,
    const float* __restrict__ b2, const float* __restrict__ w3,
    float* __restrict__ rowsum, int M)
{
    __shared__ unsigned short h1s[64 * 256];   // 32 KB, xor-swizzled
    const int tid = threadIdx.x;
    const int wave = tid >> 6;
    const int lane = tid & 63;
    const int quad = lane >> 4;
    const int l16 = lane & 15;
    const int bm = blockIdx.x * 64;
    const int nc0 = wave * 64;

    f32x4 acc[4][4];
#pragma unroll
    for (int i = 0; i < 4; ++i)
#pragma unroll
        for (int j = 0; j < 4; ++j) {
            f32x4 z = {0.f, 0.f, 0.f, 0.f};
            acc[i][j] = z;
        }

    // ---- phase 1: h1 = relu((h0 + x) @ W1^T + b1), K=128 ----
    // h0 is plane-sliced: ch = kt*32 + quad*8 -> plane = 2*kt + (quad>>1),
    // within-plane offset = (quad&1)*8. A-load step per kt = 2*PLANE.
    {
        const unsigned short* pa[4];
        const float* px[4];
        const unsigned short* pb[4];
#pragma unroll
        for (int t = 0; t < 4; ++t) {
            int m = bm + t * 16 + l16; if (m >= M) m = M - 1;
            pa[t] = h0 + ((size_t)(quad >> 1)) * PLANE + (size_t)m * 16 + (quad & 1) * 8;
            px[t] = xres + (size_t)m * 128 + quad * 8;
            int n = nc0 + t * 16 + l16;
            pb[t] = w1 + (size_t)n * 128 + quad * 8;
        }
        short8 af[2][4], bf[2][4];
#pragma unroll
        for (int t = 0; t < 4; ++t) {
            af[0][t] = addres(*reinterpret_cast<const short8*>(pa[t]), px[t]);
            bf[0][t] = *reinterpret_cast<const short8*>(pb[t]);
        }
#pragma unroll
        for (int kt = 0; kt < 4; ++kt) {
            const int cur = kt & 1, nxt = cur ^ 1;
            if (kt < 3) {
#pragma unroll
                for (int t = 0; t < 4; ++t) {
                    af[nxt][t] = addres(*reinterpret_cast<const short8*>(
                                            pa[t] + (size_t)(kt + 1) * 2 * PLANE),
                                        px[t] + (kt + 1) * 32);
                    bf[nxt][t] = *reinterpret_cast<const short8*>(pb[t] + (kt + 1) * 32);
                }
            }
#pragma unroll
            for (int i = 0; i < 4; ++i)
#pragma unroll
                for (int j = 0; j < 4; ++j)
                    acc[i][j] = __builtin_amdgcn_mfma_f32_16x16x32_bf16(af[cur][i], bf[cur][j], acc[i][j], 0, 0, 0);
        }
        // relu+bias -> swizzled LDS: (row,col) at row*256 + (((col>>3)^(row&7))<<3 | (col&7))
#pragma unroll
        for (int nt = 0; nt < 4; ++nt) {
            int col = nc0 + nt * 16 + l16;
            float bv = b1[col];
            int chunk = col >> 3, rem = col & 7;
#pragma unroll
            for (int mt = 0; mt < 4; ++mt)
#pragma unroll
                for (int r = 0; r < 4; ++r) {
                    int row = mt * 16 + quad * 4 + r;
                    h1s[row * 256 + (((chunk ^ (row & 7)) << 3) | rem)] =
                        f2b(fmaxf(acc[mt][nt][r] + bv, 0.f));
                }
        }
    }
    __syncthreads();

    // ---- phase 2: h2 = relu(h1s @ W2^T + b2), K=256, ring-3 both streams ----
#pragma unroll
    for (int i = 0; i < 4; ++i)
#pragma unroll
        for (int j = 0; j < 4; ++j) {
            f32x4 z = {0.f, 0.f, 0.f, 0.f};
            acc[i][j] = z;
        }
    {
        const unsigned short* pb[4];
#pragma unroll
        for (int t = 0; t < 4; ++t) {
            int n = nc0 + t * 16 + l16;
            pb[t] = w2 + (size_t)n * 256 + quad * 8;
        }
        short8 af[3][4], bf[3][4];
#pragma unroll
        for (int t = 0; t < 4; ++t) {
            int row = t * 16 + l16;
            af[0][t] = *reinterpret_cast<const short8*>(
                &h1s[row * 256 + ((quad ^ (row & 7)) << 3)]);
            af[1][t] = *reinterpret_cast<const short8*>(
                &h1s[row * 256 + (((4 + quad) ^ (row & 7)) << 3)]);
            bf[0][t] = *reinterpret_cast<const short8*>(pb[t]);
            bf[1][t] = *reinterpret_cast<const short8*>(pb[t] + 32);
        }
#pragma unroll
        for (int kt = 0; kt < 8; ++kt) {
            const int cu = kt % 3, nx = (kt + 2) % 3;
            if (kt + 2 < 8) {
                const int c2 = (kt + 2) * 4 + quad;
#pragma unroll
                for (int t = 0; t < 4; ++t) {
                    int row = t * 16 + l16;
                    af[nx][t] = *reinterpret_cast<const short8*>(
                        &h1s[row * 256 + ((c2 ^ (row & 7)) << 3)]);
                    bf[nx][t] = *reinterpret_cast<const short8*>(pb[t] + (kt + 2) * 32);
                }
            }
#pragma unroll
            for (int i = 0; i < 4; ++i)
#pragma unroll
                for (int j = 0; j < 4; ++j)
                    acc[i][j] = __builtin_amdgcn_mfma_f32_16x16x32_bf16(af[cu][i], bf[cu][j], acc[i][j], 0, 0, 0);
        }
    }

    // ---- fused epilogue: partial w3-dot over this wave's 64 cols ----
    float part[4][4];
#pragma unroll
    for (int mt = 0; mt < 4; ++mt)
#pragma unroll
        for (int r = 0; r < 4; ++r) part[mt][r] = 0.f;
#pragma unroll
    for (int nt = 0; nt < 4; ++nt) {
        int col = nc0 + nt * 16 + l16;
        float bs = b2[col];
        float wv3 = w3[col];
#pragma unroll
        for (int mt = 0; mt < 4; ++mt)
#pragma unroll
            for (int r = 0; r < 4; ++r)
                part[mt][r] += fmaxf(acc[mt][nt][r] + bs, 0.f) * wv3;
    }
#pragma unroll
    for (int mt = 0; mt < 4; ++mt)
#pragma unroll
        for (int r = 0; r < 4; ++r) {
            float v = part[mt][r];
            v += __shfl_xor(v, 1, 64);
            v += __shfl_xor(v, 2, 64);
            v += __shfl_xor(v, 4, 64);
            v += __shfl_xor(v, 8, 64);
            part[mt][r] = v;
        }
    if (l16 == 0) {
#pragma unroll
        for (int mt = 0; mt < 4; ++mt)
#pragma unroll
            for (int r = 0; r < 4; ++r) {
                int row = bm + mt * 16 + quad * 4 + r;
                if (row < M) rowsum[(size_t)row * 4 + wave] = part[mt][r];
            }
    }
}

// ---------------- final: out[g] = b3 + sum of 80 rowsum slots ----------------

__global__ __launch_bounds__(256) void final_k(
    const float* __restrict__ rowsum, const float* __restrict__ b3,
    float* __restrict__ out)
{
    int g = blockIdx.x * 256 + threadIdx.x;
    if (g >= NGRAPH) return;
    const float4* p = reinterpret_cast<const float4*>(rowsum + (size_t)g * 80);
    float s = 0.f;
#pragma unroll
    for (int i = 0; i < 20; ++i) {
        float4 v = p[i];
        s += (v.x + v.y) + (v.z + v.w);
    }
    out[g] = s + b3[0];
}

// ---------------- launch ----------------

extern "C" void kernel_launch(void* const* d_in, const int* in_sizes, int n_in,
                              void* d_out, int out_size, void* d_ws, size_t ws_size,
                              hipStream_t stream)
{
    const float* x      = (const float*)d_in[0];
    const int*   ei     = (const int*)  d_in[1];
    const float* conv_w = (const float*)d_in[2];
    const float* conv_b = (const float*)d_in[3];
    const float* lin1_w = (const float*)d_in[4];
    const float* lin1_b = (const float*)d_in[5];
    const float* lin2_w = (const float*)d_in[6];
    const float* lin2_b = (const float*)d_in[7];
    const float* lin3_w = (const float*)d_in[8];
    const float* lin3_b = (const float*)d_in[9];
    float* out = (float*)d_out;

    // Workspace (~81 MB):
    //   xws bf16 [8 planes x N*16] | h0 bf16 [8 planes x N*16] | entries | csr
    //   rowptr2 int2 [N] | dinv [N] | bfill [NB] | wt0/wt1/wt2 | rowsum
    unsigned short* xws     = (unsigned short*)d_ws;
    unsigned short* h0      = xws + (size_t)12800000;
    unsigned*       entries = (unsigned*)(h0 + (size_t)12800000);
    int*            csr     = (int*)(entries + (size_t)NB * CAP);
    int2*           rowptr2 = (int2*)(csr + (size_t)NB * CAP);
    float*          dinv    = (float*)(rowptr2 + NNODES);
    int*            bfill   = (int*)(dinv + NNODES);
    unsigned short* wt0     = (unsigned short*)(bfill + NB + 8);
    unsigned short* wt1     = wt0 + 16384;
    unsigned short* wt2     = wt1 + 32768;
    float*          rowsum  = (float*)(wt2 + 65536);

    // CSR build (fixed-capacity bucket windows)
    hipMemsetAsync(bfill, 0, NB * sizeof(int), stream);
    bin_k<<<BIN_WGS, 256, 0, stream>>>(ei, bfill, entries);
    bucket_build_k<<<NB, 256, 0, stream>>>(entries, bfill, rowptr2, csr, dinv);

    // weight conversions (one launch)
    cvt_w_k<<<(114688 + 255) / 256, 256, 0, stream>>>(conv_w, lin1_w, lin2_w, wt0, wt1, wt2);

    // gemm0: xws = (x @ conv_w) * dinv[row], plane-sliced layout
    mgemm0_k<<<(NNODES + 127) / 128, 256, 0, stream>>>(x, wt0, dinv, xws, NNODES);

    // gather + conv epilogue -> h0 (plane-sliced). 4-lane group per node,
    // slice = blockIdx & 7 pins each plane to one XCD's L2.
    gather_k<<<((NNODES + 63) / 64) * NSLICE, 256, 0, stream>>>(rowptr2, csr, xws, dinv,
                                                                conv_b, h0);

    // fused MLP: residual add + gemm1 -> LDS -> gemm2 -> w3-dot -> rowsum
    fmlp_k<<<(NNODES + 63) / 64, 256, 0, stream>>>(h0, x, wt1, lin1_b, wt2, lin2_b, lin3_w,
                                                   rowsum, NNODES);

    // out[g] = b3 + sum of this graph's 80 rowsum slots
    final_k<<<(NGRAPH + 255) / 256, 256, 0, stream>>>(rowsum, lin3_b, out);
}

// Round 4
// 330.374 us; speedup vs baseline: 1.3806x; 1.0009x over previous
//
#include <hip/hip_runtime.h>
#include <hip/hip_bf16.h>
#include <cstddef>

#define NNODES 100000
#define NEDGES 1600000
#define CIN 128
#define HID 256
#define ACT 20
#define NGRAPH (NNODES / ACT)
#define BSHIFT 8
#define NB ((NNODES + 255) >> 8)     // 391 buckets of 256 nodes
#define BIN_WGS 512
#define PER_WG (NEDGES / BIN_WGS)    // 3125
#define CAP 8192                     // bucket window capacity (mean fill 4096)
#define NSLICE 8
#define PROWS (NNODES + 8)           // plane rows: +1 zero row (idx NNODES) +pad
#define PLANE ((size_t)PROWS * 16)   // elements per channel-plane of xws
#define CVT_WGS 449                  // ceil(114816/256) blocks folded into bin_k

typedef __attribute__((ext_vector_type(8))) short short8;
typedef __attribute__((ext_vector_type(4))) float f32x4;
typedef __attribute__((ext_vector_type(2))) float f32x2;

__device__ __forceinline__ unsigned short f2b(float f) {
    unsigned u = __float_as_uint(f);
    u += 0x7FFF + ((u >> 16) & 1);          // round-to-nearest-even
    return (unsigned short)(u >> 16);
}
__device__ __forceinline__ f32x2 bf2up(unsigned u) {
    f32x2 r;
    r.x = __uint_as_float(u << 16);
    r.y = __uint_as_float(u & 0xffff0000u);
    return r;
}

// ------------- bucketed CSR build + weight cvt (blocks >= BIN_WGS) -----------

__global__ __launch_bounds__(256) void bin_k(const int* __restrict__ ei,
                                             int* __restrict__ bfill,
                                             unsigned* __restrict__ entries,
                                             const float* __restrict__ conv_w,
                                             const float* __restrict__ lin1_w,
                                             const float* __restrict__ lin2_w,
                                             unsigned short* __restrict__ wt0,
                                             unsigned short* __restrict__ wt1,
                                             unsigned short* __restrict__ wt2,
                                             unsigned short* __restrict__ xws) {
    __shared__ int cnt[NB], lofs[NB], base[NB], cur[NB];
    __shared__ unsigned lbuf[PER_WG];
    __shared__ int gdst[PER_WG];
    __shared__ int wsum[4];
    if (blockIdx.x >= BIN_WGS) {          // folded weight-conversion blocks
        int id = (blockIdx.x - BIN_WGS) * 256 + threadIdx.x;
        if (id < 16384) {
            int k = id >> 7, n = id & 127;
            wt0[n * 128 + k] = f2b(conv_w[k * 128 + n]);
        } else if (id < 16384 + 32768) {
            int i = id - 16384;
            wt1[i] = f2b(lin1_w[i]);
        } else if (id < 16384 + 32768 + 65536) {
            int i = id - 49152;
            wt2[i] = f2b(lin2_w[i]);
        } else if (id < 114688 + 128) {   // zero-row NNODES in each xws plane
            int i = id - 114688;
            xws[(size_t)(i >> 4) * PLANE + (size_t)NNODES * 16 + (i & 15)] = 0;
        }
        return;
    }
    const int t = threadIdx.x;
    for (int i = t; i < NB; i += 256) { cnt[i] = 0; cur[i] = 0; }
    __syncthreads();
    const int s = blockIdx.x * PER_WG;
    const int e = s + PER_WG;
    for (int i = s + t; i < e; i += 256)
        atomicAdd(&cnt[ei[NEDGES + i] >> BSHIFT], 1);
    __syncthreads();
    int c0 = (2 * t < NB) ? cnt[2 * t] : 0;
    int c1 = (2 * t + 1 < NB) ? cnt[2 * t + 1] : 0;
    int v = c0 + c1;
    int lane = t & 63, wid = t >> 6;
    int inc = v;
#pragma unroll
    for (int o = 1; o < 64; o <<= 1) {
        int tv = __shfl_up(inc, o, 64);
        if (lane >= o) inc += tv;
    }
    if (lane == 63) wsum[wid] = inc;
    __syncthreads();
    int woff = 0;
#pragma unroll
    for (int w = 0; w < 4; ++w) woff += (w < wid) ? wsum[w] : 0;
    int excl = inc + woff - v;
    if (2 * t < NB) lofs[2 * t] = excl;
    if (2 * t + 1 < NB) lofs[2 * t + 1] = excl + c0;
    __syncthreads();
    for (int b = t; b < NB; b += 256)
        base[b] = cnt[b] ? atomicAdd(&bfill[b], cnt[b]) : 0;
    __syncthreads();
    for (int i = s + t; i < e; i += 256) {
        int src = ei[i], dst = ei[NEDGES + i];
        int b = dst >> BSHIFT;
        int r = atomicAdd(&cur[b], 1);
        int slot = lofs[b] + r;
        lbuf[slot] = ((unsigned)src << 8) | (unsigned)(dst & 255);
        int g = base[b] + r;
        gdst[slot] = (g < CAP) ? (int)((size_t)b * CAP + g) : -1;
    }
    __syncthreads();
    for (int i = t; i < PER_WG; i += 256) {
        int g = gdst[i];
        if (g >= 0) entries[g] = lbuf[i];
    }
}

__global__ __launch_bounds__(256) void bucket_build_k(
    const unsigned* __restrict__ entries, const int* __restrict__ bfill,
    int2* __restrict__ rowptr2, int* __restrict__ csr, float* __restrict__ dinv) {
    const int b = blockIdx.x;
    const int count = min(bfill[b], CAP);
    const int node0 = b << BSHIFT;
    const int nn = min(256, NNODES - node0);
    const size_t gbase = (size_t)b * CAP;
    __shared__ int cnt[256], off[256], cur[256];
    const int t = threadIdx.x;
    cnt[t] = 0; cur[t] = 0;
    __syncthreads();
    for (int i = t; i < count; i += 256)
        atomicAdd(&cnt[entries[gbase + i] & 255], 1);
    __syncthreads();
    int lane = t & 63, wid = t >> 6;
    int v = cnt[t];
    int inc = v;
#pragma unroll
    for (int o = 1; o < 64; o <<= 1) {
        int tv = __shfl_up(inc, o, 64);
        if (lane >= o) inc += tv;
    }
    __shared__ int wsum[4];
    if (lane == 63) wsum[wid] = inc;
    __syncthreads();
    int woff = 0;
#pragma unroll
    for (int w = 0; w < 4; ++w) woff += (w < wid) ? wsum[w] : 0;
    int excl = inc + woff - v;
    off[t] = excl;
    if (t < nn) {
        rowptr2[node0 + t] = make_int2((int)gbase + excl, (int)gbase + excl + v);
        dinv[node0 + t] = rsqrtf(1.0f + (float)v);
    }
    __syncthreads();
    for (int i = t; i < count; i += 256) {
        unsigned en = entries[gbase + i];
        int loc = (int)(en & 255);
        int r = atomicAdd(&cur[loc], 1);
        csr[gbase + off[loc] + r] = (int)(en >> 8);
    }
}

// ---------------- MFMA bf16 GEMM for conv (fp32 A, reg-pipelined) ----------
// C-write goes to the PLANE-SLICED xws layout:
//   plane p = channels [16p, 16p+16): xws[p*PLANE + row*16 + c]

__global__ __launch_bounds__(256) void mgemm0_k(
    const float* __restrict__ Af, const unsigned short* __restrict__ B,
    const float* __restrict__ dinv, unsigned short* __restrict__ Cout, int M)
{
    const int tid = threadIdx.x;
    const int wid = tid >> 6;
    const int lane = tid & 63;
    const int quad = lane >> 4;
    const int l16 = lane & 15;
    const int bm = blockIdx.x * 128 + (wid >> 1) * 64;
    const int bn = (wid & 1) * 64;

    const float* pa[4];
    const unsigned short* pb[4];
#pragma unroll
    for (int t = 0; t < 4; ++t) {
        int m = bm + t * 16 + l16; if (m >= M) m = M - 1;   // clamp; store guarded
        pa[t] = Af + (size_t)m * 128 + quad * 8;
        int n = bn + t * 16 + l16;
        pb[t] = B + (size_t)n * 128 + quad * 8;
    }

    f32x4 acc[4][4];
#pragma unroll
    for (int i = 0; i < 4; ++i)
#pragma unroll
        for (int j = 0; j < 4; ++j) {
            f32x4 z = {0.f, 0.f, 0.f, 0.f};
            acc[i][j] = z;
        }

    float4 afl[2][4][2];
    short8 bf[2][4];
#pragma unroll
    for (int t = 0; t < 4; ++t) {
        afl[0][t][0] = *reinterpret_cast<const float4*>(pa[t]);
        afl[0][t][1] = *reinterpret_cast<const float4*>(pa[t] + 4);
        bf[0][t] = *reinterpret_cast<const short8*>(pb[t]);
    }

#pragma unroll
    for (int kt = 0; kt < 4; ++kt) {
        const int cur = kt & 1, nxt = cur ^ 1;
        if (kt < 3) {
#pragma unroll
            for (int t = 0; t < 4; ++t) {
                afl[nxt][t][0] = *reinterpret_cast<const float4*>(pa[t] + (kt + 1) * 32);
                afl[nxt][t][1] = *reinterpret_cast<const float4*>(pa[t] + (kt + 1) * 32 + 4);
                bf[nxt][t] = *reinterpret_cast<const short8*>(pb[t] + (kt + 1) * 32);
            }
        }
        short8 a[4];
#pragma unroll
        for (int t = 0; t < 4; ++t) {
            float4 f0 = afl[cur][t][0], f1 = afl[cur][t][1];
            short8 av;
            av[0] = (short)f2b(f0.x); av[1] = (short)f2b(f0.y);
            av[2] = (short)f2b(f0.z); av[3] = (short)f2b(f0.w);
            av[4] = (short)f2b(f1.x); av[5] = (short)f2b(f1.y);
            av[6] = (short)f2b(f1.z); av[7] = (short)f2b(f1.w);
            a[t] = av;
        }
#pragma unroll
        for (int i = 0; i < 4; ++i)
#pragma unroll
            for (int j = 0; j < 4; ++j)
                acc[i][j] = __builtin_amdgcn_mfma_f32_16x16x32_bf16(a[i], bf[cur][j], acc[i][j], 0, 0, 0);
    }

#pragma unroll
    for (int i = 0; i < 4; ++i)
#pragma unroll
        for (int r = 0; r < 4; ++r) {
            int row = bm + i * 16 + quad * 4 + r;
            if (row >= M) continue;
            float dv = dinv[row];
#pragma unroll
            for (int j = 0; j < 4; ++j) {
                // col = bn + j*16 + l16; plane = (bn>>4)+j; within = l16
                size_t pbase = (size_t)((bn >> 4) + j) * PLANE;
                Cout[pbase + (size_t)row * 16 + l16] = f2b(acc[i][j][r] * dv);
            }
        }
}

// ---------------- gather v9: branchless 2-deep-pipelined XCD-sliced ----------
// 4-lane group per node (lane pair owns a 16B half-row; sel picks the edge).
// Invalid edge slots load the dedicated zero-row (idx NNODES) -> unconditional
// accumulate, no exec-mask churn. Data loads for step s+1 issue before step s's
// unpack (3 VMEM in flight/lane). float2 accum -> v_pk_add_f32.
// Epilogue: relu(a*dinv + b) + x  -> h0 ROW-MAJOR.

__global__ __launch_bounds__(256) void gather_k(
    const int2* __restrict__ rowptr2, const int* __restrict__ csr,
    const unsigned short* __restrict__ xws, const float* __restrict__ dinv,
    const float* __restrict__ x, const float* __restrict__ conv_b,
    unsigned short* __restrict__ h0)
{
    const int slice = blockIdx.x & 7;
    const int ng = blockIdx.x >> 3;
    const int lane = threadIdx.x & 63;
    const int wave = threadIdx.x >> 6;
    const int node = ng * 64 + wave * 16 + (lane >> 2);
    const int cq = lane & 3;
    const int half = cq & 1;           // which 16B half-row this lane owns
    const int sel = cq >> 1;           // edge selector within a data instr
    if (node >= NNODES) return;
    const unsigned short* xp = xws + (size_t)slice * PLANE;

    const int2 se = rowptr2[node];
    const int start = se.x, end = se.y;

    f32x2 a0, a1, a2, a3;
    if (cq < 2) {   // self-loop: only the first lane-pair, to avoid double count
        uint4 v = *reinterpret_cast<const uint4*>(xp + (size_t)node * 16 + half * 8);
        a0 = bf2up(v.x); a1 = bf2up(v.y); a2 = bf2up(v.z); a3 = bf2up(v.w);
    } else {
        f32x2 z = {0.f, 0.f};
        a0 = z; a1 = z; a2 = z; a3 = z;
    }

    const int es = start & ~3;               // 16B-align the csr window
    const int nsteps = (end - es + 3) >> 2;

    uint4 inext;                             // indices for window s+1
    uint4 dc0, dc1;                          // data for window s (in flight)
    if (nsteps > 0) {
        uint4 i0 = *reinterpret_cast<const uint4*>(csr + es);
        int e0 = es + sel, e1 = es + 2 + sel;
        int r0 = (e0 >= start && e0 < end) ? (sel ? (int)i0.y : (int)i0.x) : NNODES;
        int r1 = (e1 >= start && e1 < end) ? (sel ? (int)i0.w : (int)i0.z) : NNODES;
        dc0 = *reinterpret_cast<const uint4*>(xp + (size_t)r0 * 16 + half * 8);
        dc1 = *reinterpret_cast<const uint4*>(xp + (size_t)r1 * 16 + half * 8);
        if (nsteps > 1) inext = *reinterpret_cast<const uint4*>(csr + es + 4);
    }
    for (int s = 0; s < nsteps; ++s) {
        const int e = es + s * 4;
        uint4 dn0, dn1;
        if (s + 1 < nsteps) {                // issue next window's data loads
            const int en0 = e + 4 + sel, en1 = e + 6 + sel;   // >= start always
            int rn0 = (en0 < end) ? (sel ? (int)inext.y : (int)inext.x) : NNODES;
            int rn1 = (en1 < end) ? (sel ? (int)inext.w : (int)inext.z) : NNODES;
            dn0 = *reinterpret_cast<const uint4*>(xp + (size_t)rn0 * 16 + half * 8);
            dn1 = *reinterpret_cast<const uint4*>(xp + (size_t)rn1 * 16 + half * 8);
        }
        if (s + 2 < nsteps)                  // prefetch window s+2's indices
            inext = *reinterpret_cast<const uint4*>(csr + e + 8);
        // unconditional accumulate of current window (invalid slots = zeros)
        a0 += bf2up(dc0.x); a1 += bf2up(dc0.y); a2 += bf2up(dc0.z); a3 += bf2up(dc0.w);
        a0 += bf2up(dc1.x); a1 += bf2up(dc1.y); a2 += bf2up(dc1.z); a3 += bf2up(dc1.w);
        dc0 = dn0; dc1 = dn1;
    }

    // combine the two lane-pairs (lanes cq and cq^2 hold the same half)
    float av[8] = {a0.x, a0.y, a1.x, a1.y, a2.x, a2.y, a3.x, a3.y};
#pragma unroll
    for (int i = 0; i < 8; ++i) av[i] += __shfl_xor(av[i], 2, 64);

    if (cq < 2) {
        const float dv = dinv[node];
        const float* bb = conv_b + slice * 16 + half * 8;
        const float4 b0 = *reinterpret_cast<const float4*>(bb);
        const float4 b1 = *reinterpret_cast<const float4*>(bb + 4);
        const float* xr = x + (size_t)node * 128 + slice * 16 + half * 8;
        const float4 x0 = *reinterpret_cast<const float4*>(xr);
        const float4 x1 = *reinterpret_cast<const float4*>(xr + 4);
        float o[8];
        o[0] = fmaxf(av[0] * dv + b0.x, 0.f) + x0.x;
        o[1] = fmaxf(av[1] * dv + b0.y, 0.f) + x0.y;
        o[2] = fmaxf(av[2] * dv + b0.z, 0.f) + x0.z;
        o[3] = fmaxf(av[3] * dv + b0.w, 0.f) + x0.w;
        o[4] = fmaxf(av[4] * dv + b1.x, 0.f) + x1.x;
        o[5] = fmaxf(av[5] * dv + b1.y, 0.f) + x1.y;
        o[6] = fmaxf(av[6] * dv + b1.z, 0.f) + x1.z;
        o[7] = fmaxf(av[7] * dv + b1.w, 0.f) + x1.w;
        uint4 pk;
        pk.x = (unsigned)f2b(o[0]) | ((unsigned)f2b(o[1]) << 16);
        pk.y = (unsigned)f2b(o[2]) | ((unsigned)f2b(o[3]) << 16);
        pk.z = (unsigned)f2b(o[4]) | ((unsigned)f2b(o[5]) << 16);
        pk.w = (unsigned)f2b(o[6]) | ((unsigned)f2b(o[7]) << 16);
        *reinterpret_cast<uint4*>(h0 + (size_t)node * CIN + slice * 16 + half * 8) = pk;
    }
}

// ---------------- fused MLP (round-0 form): h0 row-major, no residual ------

__global__ __launch_bounds__(256) void fmlp_k(
    const unsigned short* __restrict__ h0, const unsigned short* __restrict__ w1,
    const float* __restrict__ b1, const unsigned short* __restrict__ w2,
    const float* __restrict__ b2, const float* __restrict__ w3,
    float* __restrict__ rowsum, int M)
{
    __shared__ unsigned short h1s[64 * 256];   // 32 KB, xor-swizzled
    const int tid = threadIdx.x;
    const int wave = tid >> 6;
    const int lane = tid & 63;
    const int quad = lane >> 4;
    const int l16 = lane & 15;
    const int bm = blockIdx.x * 64;
    const int nc0 = wave * 64;

    f32x4 acc[4][4];
#pragma unroll
    for (int i = 0; i < 4; ++i)
#pragma unroll
        for (int j = 0; j < 4; ++j) {
            f32x4 z = {0.f, 0.f, 0.f, 0.f};
            acc[i][j] = z;
        }

    // ---- phase 1: h1 = relu(h0 @ W1^T + b1), K=128 ----
    {
        const unsigned short* pa[4];
        const unsigned short* pb[4];
#pragma unroll
        for (int t = 0; t < 4; ++t) {
            int m = bm + t * 16 + l16; if (m >= M) m = M - 1;
            pa[t] = h0 + (size_t)m * 128 + quad * 8;
            int n = nc0 + t * 16 + l16;
            pb[t] = w1 + (size_t)n * 128 + quad * 8;
        }
        short8 af[2][4], bf[2][4];
#pragma unroll
        for (int t = 0; t < 4; ++t) {
            af[0][t] = *reinterpret_cast<const short8*>(pa[t]);
            bf[0][t] = *reinterpret_cast<const short8*>(pb[t]);
        }
#pragma unroll
        for (int kt = 0; kt < 4; ++kt) {
            const int cur = kt & 1, nxt = cur ^ 1;
            if (kt < 3) {
#pragma unroll
                for (int t = 0; t < 4; ++t) {
                    af[nxt][t] = *reinterpret_cast<const short8*>(pa[t] + (kt + 1) * 32);
                    bf[nxt][t] = *reinterpret_cast<const short8*>(pb[t] + (kt + 1) * 32);
                }
            }
#pragma unroll
            for (int i = 0; i < 4; ++i)
#pragma unroll
                for (int j = 0; j < 4; ++j)
                    acc[i][j] = __builtin_amdgcn_mfma_f32_16x16x32_bf16(af[cur][i], bf[cur][j], acc[i][j], 0, 0, 0);
        }
        // relu+bias -> swizzled LDS: (row,col) at row*256 + (((col>>3)^(row&7))<<3 | (col&7))
#pragma unroll
        for (int nt = 0; nt < 4; ++nt) {
            int col = nc0 + nt * 16 + l16;
            float bv = b1[col];
            int chunk = col >> 3, rem = col & 7;
#pragma unroll
            for (int mt = 0; mt < 4; ++mt)
#pragma unroll
                for (int r = 0; r < 4; ++r) {
                    int row = mt * 16 + quad * 4 + r;
                    h1s[row * 256 + (((chunk ^ (row & 7)) << 3) | rem)] =
                        f2b(fmaxf(acc[mt][nt][r] + bv, 0.f));
                }
        }
    }
    __syncthreads();

    // ---- phase 2: h2 = relu(h1s @ W2^T + b2), K=256, ring-3 both streams ----
#pragma unroll
    for (int i = 0; i < 4; ++i)
#pragma unroll
        for (int j = 0; j < 4; ++j) {
            f32x4 z = {0.f, 0.f, 0.f, 0.f};
            acc[i][j] = z;
        }
    {
        const unsigned short* pb[4];
#pragma unroll
        for (int t = 0; t < 4; ++t) {
            int n = nc0 + t * 16 + l16;
            pb[t] = w2 + (size_t)n * 256 + quad * 8;
        }
        short8 af[3][4], bf[3][4];
#pragma unroll
        for (int t = 0; t < 4; ++t) {
            int row = t * 16 + l16;
            af[0][t] = *reinterpret_cast<const short8*>(
                &h1s[row * 256 + ((quad ^ (row & 7)) << 3)]);
            af[1][t] = *reinterpret_cast<const short8*>(
                &h1s[row * 256 + (((4 + quad) ^ (row & 7)) << 3)]);
            bf[0][t] = *reinterpret_cast<const short8*>(pb[t]);
            bf[1][t] = *reinterpret_cast<const short8*>(pb[t] + 32);
        }
#pragma unroll
        for (int kt = 0; kt < 8; ++kt) {
            const int cu = kt % 3, nx = (kt + 2) % 3;
            if (kt + 2 < 8) {
                const int c2 = (kt + 2) * 4 + quad;
#pragma unroll
                for (int t = 0; t < 4; ++t) {
                    int row = t * 16 + l16;
                    af[nx][t] = *reinterpret_cast<const short8*>(
                        &h1s[row * 256 + ((c2 ^ (row & 7)) << 3)]);
                    bf[nx][t] = *reinterpret_cast<const short8*>(pb[t] + (kt + 2) * 32);
                }
            }
#pragma unroll
            for (int i = 0; i < 4; ++i)
#pragma unroll
                for (int j = 0; j < 4; ++j)
                    acc[i][j] = __builtin_amdgcn_mfma_f32_16x16x32_bf16(af[cu][i], bf[cu][j], acc[i][j], 0, 0, 0);
        }
    }

    // ---- fused epilogue: partial w3-dot over this wave's 64 cols ----
    float part[4][4];
#pragma unroll
    for (int mt = 0; mt < 4; ++mt)
#pragma unroll
        for (int r = 0; r < 4; ++r) part[mt][r] = 0.f;
#pragma unroll
    for (int nt = 0; nt < 4; ++nt) {
        int col = nc0 + nt * 16 + l16;
        float bs = b2[col];
        float wv3 = w3[col];
#pragma unroll
        for (int mt = 0; mt < 4; ++mt)
#pragma unroll
            for (int r = 0; r < 4; ++r)
                part[mt][r] += fmaxf(acc[mt][nt][r] + bs, 0.f) * wv3;
    }
#pragma unroll
    for (int mt = 0; mt < 4; ++mt)
#pragma unroll
        for (int r = 0; r < 4; ++r) {
            float v = part[mt][r];
            v += __shfl_xor(v, 1, 64);
            v += __shfl_xor(v, 2, 64);
            v += __shfl_xor(v, 4, 64);
            v += __shfl_xor(v, 8, 64);
            part[mt][r] = v;
        }
    if (l16 == 0) {
#pragma unroll
        for (int mt = 0; mt < 4; ++mt)
#pragma unroll
            for (int r = 0; r < 4; ++r) {
                int row = bm + mt * 16 + quad * 4 + r;
                if (row < M) rowsum[(size_t)row * 4 + wave] = part[mt][r];
            }
    }
}

// ---------------- final: out[g] = b3 + sum of 80 rowsum slots ----------------

__global__ __launch_bounds__(256) void final_k(
    const float* __restrict__ rowsum, const float* __restrict__ b3,
    float* __restrict__ out)
{
    int g = blockIdx.x * 256 + threadIdx.x;
    if (g >= NGRAPH) return;
    const float4* p = reinterpret_cast<const float4*>(rowsum + (size_t)g * 80);
    float s = 0.f;
#pragma unroll
    for (int i = 0; i < 20; ++i) {
        float4 v = p[i];
        s += (v.x + v.y) + (v.z + v.w);
    }
    out[g] = s + b3[0];
}

// ---------------- launch ----------------

extern "C" void kernel_launch(void* const* d_in, const int* in_sizes, int n_in,
                              void* d_out, int out_size, void* d_ws, size_t ws_size,
                              hipStream_t stream)
{
    const float* x      = (const float*)d_in[0];
    const int*   ei     = (const int*)  d_in[1];
    const float* conv_w = (const float*)d_in[2];
    const float* conv_b = (const float*)d_in[3];
    const float* lin1_w = (const float*)d_in[4];
    const float* lin1_b = (const float*)d_in[5];
    const float* lin2_w = (const float*)d_in[6];
    const float* lin2_b = (const float*)d_in[7];
    const float* lin3_w = (const float*)d_in[8];
    const float* lin3_b = (const float*)d_in[9];
    float* out = (float*)d_out;

    // Workspace (~81 MB):
    //   xws bf16 [8 planes x PROWS*16] | h0 bf16 [N*128 row-major] | entries | csr
    //   rowptr2 int2 [N] | dinv [N] | bfill [NB] | wt0/wt1/wt2 | rowsum
    unsigned short* xws     = (unsigned short*)d_ws;
    unsigned short* h0      = xws + (size_t)NSLICE * PLANE;          // 12,801,024
    unsigned*       entries = (unsigned*)(h0 + (size_t)12800000);
    int*            csr     = (int*)(entries + (size_t)NB * CAP);
    int2*           rowptr2 = (int2*)(csr + (size_t)NB * CAP);
    float*          dinv    = (float*)(rowptr2 + NNODES);
    int*            bfill   = (int*)(dinv + NNODES);
    unsigned short* wt0     = (unsigned short*)(bfill + NB + 8);
    unsigned short* wt1     = wt0 + 16384;
    unsigned short* wt2     = wt1 + 32768;
    float*          rowsum  = (float*)(wt2 + 65536);

    // CSR build (fixed-capacity bucket windows) + folded weight conversions
    hipMemsetAsync(bfill, 0, NB * sizeof(int), stream);
    bin_k<<<BIN_WGS + CVT_WGS, 256, 0, stream>>>(ei, bfill, entries,
                                                 conv_w, lin1_w, lin2_w,
                                                 wt0, wt1, wt2, xws);
    bucket_build_k<<<NB, 256, 0, stream>>>(entries, bfill, rowptr2, csr, dinv);

    // gemm0: xws = (x @ conv_w) * dinv[row], plane-sliced layout
    mgemm0_k<<<(NNODES + 127) / 128, 256, 0, stream>>>(x, wt0, dinv, xws, NNODES);

    // gather + conv epilogue + residual -> h0 row-major
    gather_k<<<((NNODES + 63) / 64) * NSLICE, 256, 0, stream>>>(rowptr2, csr, xws, dinv,
                                                                x, conv_b, h0);

    // fused MLP: gemm1 -> LDS -> gemm2 -> w3-dot -> rowsum
    fmlp_k<<<(NNODES + 63) / 64, 256, 0, stream>>>(h0, wt1, lin1_b, wt2, lin2_b, lin3_w,
                                                   rowsum, NNODES);

    // out[g] = b3 + sum of this graph's 80 rowsum slots
    final_k<<<(NGRAPH + 255) / 256, 256, 0, stream>>>(rowsum, lin3_b, out);
}